// Round 5
// baseline (1107.985 us; speedup 1.0000x reference)
//
#include <hip/hip_runtime.h>
#include <math.h>

typedef unsigned int   u32;
typedef unsigned short u16;
typedef short bf16x8 __attribute__((ext_vector_type(8)));
typedef float f32x4  __attribute__((ext_vector_type(4)));

// ---- output element offsets (d_out is FLOAT32, 101760 elements) ----
#define OUT_ZS    0
#define OUT_PS    3810
#define OUT_AALL  41910
#define OUT_A     43830
#define OUT_C     82230
#define OUT_LASTZ 101430
#define OUT_LASTP 101460

__device__ __forceinline__ float sigm(float x){ return 1.f/(1.f+expf(-x)); }
__device__ __forceinline__ float safed(float d){
    return (fabsf(d) < 1e-30f) ? ((d < 0.f) ? -1e-30f : 1e-30f) : d;
}
__device__ __forceinline__ u16 f2b(float f) {
    union { float f; u32 u; } v; v.f = f;
    u32 r = v.u + 0x7fffu + ((v.u >> 16) & 1u);   // RNE
    return (u16)(r >> 16);
}
__device__ __forceinline__ float b2f(u16 u) {
    union { u32 x; float f; } v; v.x = ((u32)u) << 16; return v.f;
}
__device__ __forceinline__ u32 packb(float a, float b){ return (u32)f2b(a) | ((u32)f2b(b) << 16); }

// ---- static device workspace ----
__device__ u16   r14_c1[25165824];   // conv1 out bf16 NHWC [384][32][32][64]
__device__ u16   r14_c2[12582912];   // conv2 out bf16 NHWC [384][16][16][128]
__device__ float r14_c3[12582912];   // conv3 out fp32 NHWC [384][8][8][512]
__device__ u16   r14_w2h[131072];    // w2T hi bf16 [128 oc][1024 k]
__device__ u16   r14_w2l[131072];    // w2T lo bf16
__device__ u16   r14_w3h[1048576];   // w3T hi bf16 [512 oc][2048 k]
__device__ u16   r14_w3l[1048576];   // w3T lo bf16
__device__ float r14_wdT[163840];    // [5][32768]
__device__ float r14_hs[49152];
__device__ float r14_zhat[3840];
__device__ float r14_phat[38400];
__device__ float r14_pz[3840];
__device__ float r14_pp[38400];
__device__ float r14_aall[1920];
__device__ float r14_A[38400];
__device__ float r14_C[19200];
__device__ float r14_G[38400];

// ============================ conv1 (fp32 VALU, bf16 NHWC out) ============================
__global__ __launch_bounds__(256) void conv1_r14(const float* __restrict__ img,
        const float* __restrict__ w1, const float* __restrict__ b1, u16* __restrict__ out)
{
    __shared__ float in_lds[66*66];
    const int f = blockIdx.x, tid = threadIdx.x;
    const int og = tid >> 5, sg = tid & 31;

    for (int i = tid; i < 66*66; i += 256) in_lds[i] = 0.f;
    __syncthreads();
    const float4* src = (const float4*)(img + f*4096);
    for (int i = tid; i < 1024; i += 256) {
        int r = i >> 4, c0 = (i & 15) * 4;
        float4 v = src[i];
        float* dst = &in_lds[(r+1)*66 + c0 + 1];
        dst[0]=v.x; dst[1]=v.y; dst[2]=v.z; dst[3]=v.w;
    }
    float wr[16][8];
    #pragma unroll
    for (int k = 0; k < 16; k++) {
        float4 a = *(const float4*)&w1[k*64 + og*8];
        float4 b = *(const float4*)&w1[k*64 + og*8 + 4];
        wr[k][0]=a.x; wr[k][1]=a.y; wr[k][2]=a.z; wr[k][3]=a.w;
        wr[k][4]=b.x; wr[k][5]=b.y; wr[k][6]=b.z; wr[k][7]=b.w;
    }
    float bias[8];
    #pragma unroll
    for (int j = 0; j < 8; j++) bias[j] = b1[og*8+j];
    __syncthreads();

    for (int yy = 0; yy < 32; yy++) {
        float inv[16];
        #pragma unroll
        for (int ky = 0; ky < 4; ky++)
            #pragma unroll
            for (int kx = 0; kx < 4; kx++)
                inv[ky*4+kx] = in_lds[(2*yy+ky)*66 + 2*sg+kx];
        float acc[8];
        #pragma unroll
        for (int j = 0; j < 8; j++) acc[j] = bias[j];
        #pragma unroll
        for (int k = 0; k < 16; k++)
            #pragma unroll
            for (int j = 0; j < 8; j++) acc[j] += inv[k]*wr[k][j];
        #pragma unroll
        for (int j = 0; j < 8; j++) acc[j] = fmaxf(acc[j], 0.f);
        uint4 pk = make_uint4(packb(acc[0],acc[1]), packb(acc[2],acc[3]),
                              packb(acc[4],acc[5]), packb(acc[6],acc[7]));
        *(uint4*)(out + (f*1024 + yy*32 + sg)*64 + og*8) = pk;
    }
}

// ============================ weight transpose + bf16 split ============================
__global__ __launch_bounds__(256) void w2t_r14(const float* __restrict__ w2,
        u16* __restrict__ hi, u16* __restrict__ lo)
{
    int idx = blockIdx.x*256 + threadIdx.x;
    if (idx < 131072) {
        int k = idx >> 7, oc = idx & 127;
        float v = w2[idx];
        u16 h = f2b(v);
        hi[oc*1024 + k] = h;
        lo[oc*1024 + k] = f2b(v - b2f(h));
    }
}
__global__ __launch_bounds__(256) void w3t_r14(const float* __restrict__ w3,
        u16* __restrict__ hi, u16* __restrict__ lo)
{
    int idx = blockIdx.x*256 + threadIdx.x;
    if (idx < 1048576) {
        int k = idx >> 9, oc = idx & 511;
        float v = w3[idx];
        u16 h = f2b(v);
        hi[oc*2048 + k] = h;
        lo[oc*2048 + k] = f2b(v - b2f(h));
    }
}
__global__ __launch_bounds__(256) void wdt_r14(const float* __restrict__ wd, float* __restrict__ wdT)
{
    int idx = blockIdx.x*256 + threadIdx.x;
    if (idx < 163840) {
        int j = idx & 32767, d = idx >> 15;
        wdT[d*32768 + j] = wd[j*20 + d];
    }
}

// ============================ conv2 MFMA (r19: persistent quarter-frame tile, barrier-free K-loop) ============================
// grid (4, 384): blockIdx.x = quarter (4 output rows), blockIdx.y = frame.
// Tile: [320 slots = 10 rows x 32 cols][36 u16] (32 ic per half, stride-72B bank spread).
// 2 ic-halves: {stage, barrier, 16 taps barrier-free} x2. OOB rows staged zero; OOB cols masked in regs.
__global__ __launch_bounds__(256) void conv2_r19(const u16* __restrict__ c1b,
        const u16* __restrict__ w2h, const u16* __restrict__ w2l,
        const float* __restrict__ b2, u16* __restrict__ c2b)
{
    __shared__ __align__(16) u16 tile[320*36];
    const int qy = blockIdx.x, f = blockIdx.y, tid = threadIdx.x;
    const int wave = tid >> 6, lane = tid & 63, quad = lane >> 4, ln = lane & 15;
    const int y0 = qy*4;

    f32x4 acc[4][2];
    const f32x4 zz = {0.f, 0.f, 0.f, 0.f};
    #pragma unroll
    for (int mt = 0; mt < 4; mt++) { acc[mt][0] = zz; acc[mt][1] = zz; }

    const bf16x8 z8 = {0,0,0,0,0,0,0,0};

    for (int ich = 0; ich < 2; ich++) {
        if (ich) __syncthreads();          // all reads of half 0 done before overwrite
        // stage 320 slots x 4 chunks(16B) = 1280 chunk-writes / 256 thr = 5 each
        #pragma unroll
        for (int i = 0; i < 5; i++) {
            const int q = i*256 + tid;
            const int s = q >> 2, ch = q & 3;
            const int r = s >> 5, ix = s & 31;
            const int iy = 2*y0 - 1 + r;
            uint4 v = make_uint4(0,0,0,0);
            if ((unsigned)iy < 32u)
                v = *(const uint4*)&c1b[((f*32 + iy)*32 + ix)*64 + ich*32 + ch*8];
            *(uint4*)&tile[s*36 + ch*8] = v;
        }
        __syncthreads();

        #pragma unroll 4
        for (int kk = 0; kk < 16; kk++) {
            const int ky = kk >> 2, kx = kk & 3;
            const int ix = 2*ln - 1 + kx;          // px = ln (0..15)
            const bool vx = (unsigned)ix < 32u;
            bf16x8 af[4];
            #pragma unroll
            for (int mt = 0; mt < 4; mt++) {
                const int s = (2*mt + ky)*32 + (ix & 31);   // rloc in 0..9 always
                bf16x8 v = *(const bf16x8*)&tile[s*36 + quad*8];
                af[mt] = vx ? v : z8;
            }
            const int kb = kk*64 + ich*32 + quad*8;
            #pragma unroll
            for (int nt = 0; nt < 2; nt++) {
                const int oc = wave*32 + nt*16 + ln;
                bf16x8 bh = *(const bf16x8*)&w2h[oc*1024 + kb];
                bf16x8 bl = *(const bf16x8*)&w2l[oc*1024 + kb];
                #pragma unroll
                for (int mt = 0; mt < 4; mt++) {
                    acc[mt][nt] = __builtin_amdgcn_mfma_f32_16x16x32_bf16(af[mt], bh, acc[mt][nt], 0,0,0);
                    acc[mt][nt] = __builtin_amdgcn_mfma_f32_16x16x32_bf16(af[mt], bl, acc[mt][nt], 0,0,0);
                }
            }
        }
    }

    #pragma unroll
    for (int nt = 0; nt < 2; nt++) {
        const int oc = wave*32 + nt*16 + ln;
        const float bias = b2[oc];
        #pragma unroll
        for (int mt = 0; mt < 4; mt++)
            #pragma unroll
            for (int r = 0; r < 4; r++) {
                const int pix = (y0 + mt)*16 + quad*4 + r;   // row y0+mt, col quad*4+r..  p = mt*16 + (quad*4+r)
                c2b[(f*256 + pix)*128 + oc] = f2b(fmaxf(acc[mt][nt][r] + bias, 0.f));
            }
    }
}

// ============================ conv3 MFMA (r19: persistent full-frame tile, barrier-free K-loop) ============================
// grid (2, 384): blockIdx.x = ocg (256 oc), blockIdx.y = frame.
// Tile: [256 slots = 16x16 pixels][72 u16] (64 ic per half, stride-144B bank spread).
// 2 ic-halves: {stage, barrier, 16 taps barrier-free} x2. Halo handled by register masking.
__global__ __launch_bounds__(256) void conv3_r19(const u16* __restrict__ c2b,
        const u16* __restrict__ w3h, const u16* __restrict__ w3l,
        const float* __restrict__ b3, float* __restrict__ c3)
{
    __shared__ __align__(16) u16 tile[256*72];
    const int ocg = blockIdx.x, f = blockIdx.y, tid = threadIdx.x;
    const int wave = tid >> 6, lane = tid & 63, quad = lane >> 4, ln = lane & 15;
    const int wn = ocg*256 + wave*64;
    const int px = ln & 7, lyb = ln >> 3;

    f32x4 acc[4][4];
    const f32x4 zz = {0.f, 0.f, 0.f, 0.f};
    #pragma unroll
    for (int mt = 0; mt < 4; mt++)
        #pragma unroll
        for (int nt = 0; nt < 4; nt++) acc[mt][nt] = zz;

    const bf16x8 z8 = {0,0,0,0,0,0,0,0};

    for (int ich = 0; ich < 2; ich++) {
        if (ich) __syncthreads();
        // stage 256 slots x 8 chunks(16B) = 2048 / 256 thr = 8 each
        #pragma unroll
        for (int i = 0; i < 8; i++) {
            const int q = i*256 + tid;
            const int s = q >> 3, ch = q & 7;
            uint4 v = *(const uint4*)&c2b[(f*256 + s)*128 + ich*64 + ch*8];
            *(uint4*)&tile[s*72 + ch*8] = v;
        }
        __syncthreads();

        #pragma unroll 4
        for (int kk = 0; kk < 16; kk++) {
            const int ky = kk >> 2, kx = kk & 3;
            const int ix = 2*px - 1 + kx;
            const bool vx = (unsigned)ix < 16u;
            int sbase[4]; bool vm[4];
            #pragma unroll
            for (int mt = 0; mt < 4; mt++) {
                const int ly = 2*mt + lyb;
                const int iy = 2*ly - 1 + ky;
                vm[mt] = vx && ((unsigned)iy < 16u);
                sbase[mt] = ((iy & 15)*16 + (ix & 15))*72;
            }
            #pragma unroll
            for (int ks = 0; ks < 2; ks++) {
                bf16x8 af[4];
                #pragma unroll
                for (int mt = 0; mt < 4; mt++) {
                    bf16x8 v = *(const bf16x8*)&tile[sbase[mt] + (ks*4 + quad)*8];
                    af[mt] = vm[mt] ? v : z8;
                }
                const int kb = kk*128 + ich*64 + ks*32 + quad*8;
                #pragma unroll
                for (int nt = 0; nt < 4; nt++) {
                    const int oc = wn + nt*16 + ln;
                    bf16x8 bh = *(const bf16x8*)&w3h[oc*2048 + kb];
                    bf16x8 bl = *(const bf16x8*)&w3l[oc*2048 + kb];
                    #pragma unroll
                    for (int mt = 0; mt < 4; mt++) {
                        acc[mt][nt] = __builtin_amdgcn_mfma_f32_16x16x32_bf16(af[mt], bh, acc[mt][nt], 0,0,0);
                        acc[mt][nt] = __builtin_amdgcn_mfma_f32_16x16x32_bf16(af[mt], bl, acc[mt][nt], 0,0,0);
                    }
                }
            }
        }
    }

    #pragma unroll
    for (int nt = 0; nt < 4; nt++) {
        const int oc = wn + nt*16 + ln;
        const float bias = b3[oc];
        #pragma unroll
        for (int mt = 0; mt < 4; mt++)
            #pragma unroll
            for (int r = 0; r < 4; r++) {
                const int pix = mt*16 + quad*4 + r;
                c3[(f*64 + pix)*512 + oc] = fmaxf(acc[mt][nt][r] + bias, 0.f);
            }
    }
}

// ============================ dense -> a_all ============================
__global__ __launch_bounds__(256) void dense_r14(const float* __restrict__ bd,
        float* __restrict__ dout)
{
    const int f = blockIdx.x, tid = threadIdx.x;
    float p0=0,p1=0,p2=0,p3=0,p4=0;
    const float4* x4 = (const float4*)(r14_c3 + f*32768);
    for (int j = tid; j < 8192; j += 256) {
        float4 v = x4[j];
        float4 w0 = *(const float4*)&r14_wdT[          4*j];
        float4 w1 = *(const float4*)&r14_wdT[32768   + 4*j];
        float4 w2 = *(const float4*)&r14_wdT[65536   + 4*j];
        float4 w3 = *(const float4*)&r14_wdT[98304   + 4*j];
        float4 w4 = *(const float4*)&r14_wdT[131072  + 4*j];
        p0 += v.x*w0.x + v.y*w0.y + v.z*w0.z + v.w*w0.w;
        p1 += v.x*w1.x + v.y*w1.y + v.z*w1.z + v.w*w1.w;
        p2 += v.x*w2.x + v.y*w2.y + v.z*w2.z + v.w*w2.w;
        p3 += v.x*w3.x + v.y*w3.y + v.z*w3.z + v.w*w3.w;
        p4 += v.x*w4.x + v.y*w4.y + v.z*w4.z + v.w*w4.w;
    }
    __shared__ float red[5][256];
    red[0][tid]=p0; red[1][tid]=p1; red[2][tid]=p2; red[3][tid]=p3; red[4][tid]=p4;
    __syncthreads();
    for (int st = 128; st > 0; st >>= 1) {
        if (tid < st) {
            #pragma unroll
            for (int d = 0; d < 5; d++) red[d][tid] += red[d][tid+st];
        }
        __syncthreads();
    }
    if (tid < 5) {
        float v = red[tid][0] + bd[tid];
        r14_aall[f*5 + tid] = v;
        dout[OUT_AALL + f*5 + tid] = v;
    }
}

// ============================ LSTM (512 thr, weights in registers) ============================
__global__ __launch_bounds__(512) void lstm_r14(const float* __restrict__ lk,
        const float* __restrict__ lrk, const float* __restrict__ lb)
{
    const int b = blockIdx.x, c = threadIdx.x;   // c = gate column 0..511
    __shared__ float a_lds[640];
    __shared__ float h_lds[128];
    __shared__ float g_lds[512];
    for (int i = c; i < 640; i += 512) a_lds[i] = r14_aall[b*640 + i];
    if (c < 128) h_lds[c] = 0.f;
    float wreg[128];                    // lrk column resident in VGPRs
    #pragma unroll
    for (int j = 0; j < 128; j++) wreg[j] = lrk[j*512 + c];
    float lkr[5];
    #pragma unroll
    for (int d = 0; d < 5; d++) lkr[d] = lk[d*512 + c];
    const float gb = lb[c];
    float cs = 0.f;
    __syncthreads();
    for (int t = 0; t < 128; t++) {
        float g = gb;
        if (t > 0) {
            #pragma unroll
            for (int d = 0; d < 5; d++) g += a_lds[(t-1)*5 + d] * lkr[d];
        }
        float s0=0.f, s1=0.f, s2=0.f, s3=0.f;   // 4 chains to break fp-add dependence
        #pragma unroll
        for (int j = 0; j < 128; j += 4) {
            float4 h4 = *(const float4*)&h_lds[j];
            s0 += h4.x*wreg[j];   s1 += h4.y*wreg[j+1];
            s2 += h4.z*wreg[j+2]; s3 += h4.w*wreg[j+3];
        }
        g += (s0 + s1) + (s2 + s3);
        g_lds[c] = g;
        __syncthreads();
        if (c < 128) {
            float gi = g_lds[c], gf = g_lds[c+128], gg = g_lds[c+256], go = g_lds[c+384];
            cs = sigm(gf)*cs + sigm(gi)*tanhf(gg);
            float hn = sigm(go)*tanhf(cs);
            h_lds[c] = hn;
            r14_hs[(t*3 + b)*128 + c] = hn;
        }
        __syncthreads();
    }
}

// ============================ abc -> A, C ============================
__global__ __launch_bounds__(192) void abc_r14(const float* __restrict__ wabc,
        const float* __restrict__ babc, float* __restrict__ dout)
{
    const int tb = blockIdx.x, c = threadIdx.x;
    __shared__ float h_lds[128];
    if (c < 128) h_lds[c] = r14_hs[tb*128 + c];
    __syncthreads();
    if (c < 150) {
        float s = babc[c];
        for (int j = 0; j < 128; j++) s += h_lds[j]*wabc[j*150 + c];
        if (c < 100) { r14_A[tb*100 + c] = s; dout[OUT_A + tb*100 + c] = s; }
        else         { r14_C[tb*50 + (c-100)] = s; dout[OUT_C + tb*50 + (c-100)] = s; }
    }
}

// ============================ Kalman filter (r15: 6-phase, in-register solve, prefetch) ============================
__global__ __launch_bounds__(128) void kf_r15(float* __restrict__ dout)
{
    const int b = blockIdx.x, tid = threadIdx.x;
    const int i10 = tid/10, j10 = tid%10;
    __shared__ float Ab[2][100], Cb[2][56], avb[2][8];
    __shared__ float z[12], P[100], zh[12], AP[100], Ph[100], resid[8],
                     CPm[52], PCt[52], Ssh[28], Kg[52];

    // prologue: init state, stage t=0, issue prefetch of t=1
    float rA = 0.f, rC = 0.f, rav = 0.f;
    if (tid < 100) rA  = r14_A[(0*3+b)*100 + tid];
    if (tid < 50)  rC  = r14_C[(0*3+b)*50 + tid];
    if (tid < 5)   rav = r14_aall[(b*128+0)*5 + tid];
    if (tid < 100) P[tid] = (i10==j10) ? 1.f : 0.f;
    if (tid < 10)  z[tid] = 0.f;
    if (tid < 100) Ab[0][tid] = rA;
    if (tid < 50)  Cb[0][tid] = rC;
    if (tid < 5)   avb[0][tid] = rav;
    if (tid < 100) rA  = r14_A[(1*3+b)*100 + tid];
    if (tid < 50)  rC  = r14_C[(1*3+b)*50 + tid];
    if (tid < 5)   rav = r14_aall[(b*128+1)*5 + tid];
    __syncthreads();

    for (int t = 0; t < 128; t++) {
        const int cb = t & 1, nb = cb ^ 1;
        const float* Ax = Ab[cb];
        const float* Cx = Cb[cb];

        // P1: AP = A@P (lanes 0-99) || zh = A@z (lanes 100-109)
        if (tid < 100) {
            float s = 0.f;
            #pragma unroll
            for (int k = 0; k < 10; k++) s += Ax[i10*10+k]*P[k*10+j10];
            AP[tid] = s;
        } else if (tid < 110) {
            const int i = tid - 100;
            float s = 0.f;
            #pragma unroll
            for (int k = 0; k < 10; k++) s += Ax[i*10+k]*z[k];
            zh[i] = s;
        }
        __syncthreads();

        // P2: Ph = AP@A^T + Q (lanes 0-99) || resid = a - C@zh (lanes 100-104)
        if (tid < 100) {
            float s = (i10==j10) ? 0.08f : 0.f;
            #pragma unroll
            for (int k = 0; k < 10; k++) s += AP[i10*10+k]*Ax[j10*10+k];
            Ph[tid] = s;
        } else if (tid < 105) {
            const int c = tid - 100;
            float s = avb[cb][c];
            #pragma unroll
            for (int k = 0; k < 10; k++) s -= Cx[c*10+k]*zh[k];
            resid[c] = s;
        }
        __syncthreads();

        // P3: CPm = C@Ph (lanes 0-49) || PCt = Ph@C^T (lanes 64-113)
        if (tid < 50) {
            const int i = tid/10, j = tid%10;
            float s = 0.f;
            #pragma unroll
            for (int k = 0; k < 10; k++) s += Cx[i*10+k]*Ph[k*10+j];
            CPm[tid] = s;
        } else if (tid >= 64 && tid < 114) {
            const int q = tid-64, i = q/5, j = q%5;
            float s = 0.f;
            #pragma unroll
            for (int k = 0; k < 10; k++) s += Ph[i*10+k]*Cx[j*10+k];
            PCt[q] = s;
        }
        __syncthreads();

        // P4: S = CPm@C^T + R (lanes 0-24)
        if (tid < 25) {
            const int i = tid/5, j = tid%5;
            float s = (i==j) ? 0.03f : 0.f;
            #pragma unroll
            for (int k = 0; k < 10; k++) s += CPm[i*10+k]*Cx[j*10+k];
            Ssh[tid] = s;
        }
        __syncthreads();

        // P5: lanes 0-9 each solve S^T y = PCt[i,:]^T entirely in registers -> K row i
        if (tid < 10) {
            float M[5][5], bb[5], pv[5], x[5];
            #pragma unroll
            for (int r = 0; r < 5; r++)
                #pragma unroll
                for (int c = 0; c < 5; c++) M[r][c] = Ssh[c*5+r];   // M = S^T
            #pragma unroll
            for (int k = 0; k < 5; k++) bb[k] = PCt[tid*5+k];
            #pragma unroll
            for (int k = 0; k < 5; k++) {
                const float p = 1.f/safed(M[k][k]);
                pv[k] = p;
                #pragma unroll
                for (int r = k+1; r < 5; r++) {
                    const float f = M[r][k]*p;
                    #pragma unroll
                    for (int c = k+1; c < 5; c++) M[r][c] -= f*M[k][c];
                    bb[r] -= f*bb[k];
                }
            }
            #pragma unroll
            for (int k = 4; k >= 0; k--) {
                float s = bb[k];
                #pragma unroll
                for (int c = k+1; c < 5; c++) s -= M[k][c]*x[c];
                x[k] = s*pv[k];
            }
            #pragma unroll
            for (int k = 0; k < 5; k++) Kg[tid*5+k] = x[k];
        }
        __syncthreads();

        // P6: Pn = Ph - K@CPm -> P, pz = zh + K@resid -> z, all stores, next-tile staging
        if (tid < 100) {
            float s = Ph[tid];
            #pragma unroll
            for (int k = 0; k < 5; k++) s -= Kg[i10*5+k]*CPm[k*10+j10];
            r14_pp[(t*3+b)*100 + tid] = s;
            P[tid] = s;
            r14_phat[(t*3+b)*100 + tid] = fmaxf(Ph[tid], (i10==j10)?1e-4f:0.f);
            if (tid < 10) r14_zhat[(t*3+b)*10 + tid] = zh[tid];
        } else if (tid < 110) {
            const int i = tid - 100;
            float s = zh[i];
            #pragma unroll
            for (int k = 0; k < 5; k++) s += Kg[i*5+k]*resid[k];
            r14_pz[(t*3+b)*10 + i] = s;
            z[i] = s;
        }
        if (t < 127) {
            if (tid < 100) Ab[nb][tid] = rA;
            if (tid < 50)  Cb[nb][tid] = rC;
            if (tid < 5)   avb[nb][tid] = rav;
            if (t < 126) {
                if (tid < 100) rA  = r14_A[((t+2)*3+b)*100 + tid];
                if (tid < 50)  rC  = r14_C[((t+2)*3+b)*50 + tid];
                if (tid < 5)   rav = r14_aall[(b*128+(t+2))*5 + tid];
            }
        }
        __syncthreads();
    }
    if (tid < 10)  dout[OUT_LASTZ + b*10 + tid]  = z[tid];
    if (tid < 100) dout[OUT_LASTP + b*100 + tid] = P[tid];
}

// ============================ G = A^T @ inv(Phat_clamped) ============================
__global__ __launch_bounds__(256) void ginv_r14()
{
    const int idx = blockIdx.x;
    const int tt = idx/3 + 1, b = idx%3;
    const int tid = threadIdx.x;
    __shared__ float M[10][21];
    __shared__ float A[100];
    __shared__ int piv;
    if (tid < 100) {
        int i = tid/10, j = tid%10;
        M[i][j] = r14_phat[(tt*3+b)*100 + tid];
        M[i][10+j] = (i==j) ? 1.f : 0.f;
        A[tid] = r14_A[(tt*3+b)*100 + tid];
    }
    __syncthreads();
    const int r = tid/20, cc = tid%20;
    for (int k = 0; k < 10; k++) {
        if (tid == 0) {
            int p = k; float best = fabsf(M[k][k]);
            for (int rr = k+1; rr < 10; rr++) {
                float v = fabsf(M[rr][k]);
                if (v > best) { best = v; p = rr; }
            }
            piv = p;
        }
        __syncthreads();
        if (piv != k && tid < 20) {
            float a = M[k][tid], bb = M[piv][tid];
            M[k][tid] = bb; M[piv][tid] = a;
        }
        __syncthreads();
        float pinv = 1.f/safed(M[k][k]);
        float myf = 0.f, rowv = 0.f;
        if (tid < 200) { myf = M[r][k]; rowv = M[k][cc]; }
        __syncthreads();
        if (tid < 200) {
            if (r == k) M[k][cc] = rowv*pinv;
            else        M[r][cc] -= myf*pinv*rowv;
        }
        __syncthreads();
    }
    if (tid < 100) {
        int i = tid/10, j = tid%10;
        float s = 0.f;
        #pragma unroll
        for (int k = 0; k < 10; k++) s += A[k*10+i]*M[k][10+j];
        r14_G[(tt*3+b)*100 + tid] = s;
    }
}

// ============================ RTS smoother ============================
__global__ __launch_bounds__(128) void rts_r14(float* __restrict__ dout)
{
    const int b = blockIdx.x, tid = threadIdx.x;
    const int i10 = tid/10, j10 = tid%10;
    __shared__ float zc[10], Pc[100], D[100], Gt[100], pPm[100], ph[100],
                     zh[10], pzv[10], dz[10], T1[100], zn[10], Pnn[100];
    if (tid < 10)  zc[tid] = r14_pz[(127*3+b)*10 + tid];
    if (tid < 100) Pc[tid] = r14_pp[(127*3+b)*100 + tid];
    for (int t = 126; t >= 0; t--) {
        __syncthreads();
        if (tid < 100) {
            Gt[tid]  = r14_G[((t+1)*3+b)*100 + tid];
            pPm[tid] = r14_pp[(t*3+b)*100 + tid];
            ph[tid]  = r14_phat[((t+1)*3+b)*100 + tid];
        }
        if (tid < 10) {
            zh[tid]  = r14_zhat[((t+1)*3+b)*10 + tid];
            pzv[tid] = r14_pz[(t*3+b)*10 + tid];
        }
        __syncthreads();
        if (tid < 100){ float s=0.f; for (int k=0;k<10;k++) s += pPm[i10*10+k]*Gt[k*10+j10]; D[tid]=s; }
        if (tid < 10) dz[tid] = zc[tid] - zh[tid];
        __syncthreads();
        if (tid < 10) { float s=pzv[tid]; for (int k=0;k<10;k++) s += D[tid*10+k]*dz[k]; zn[tid]=s; }
        if (tid < 100){ float s=0.f; for (int k=0;k<10;k++) s += D[i10*10+k]*(Pc[k*10+j10]-ph[k*10+j10]); T1[tid]=s; }
        __syncthreads();
        if (tid < 100){ float s=pPm[tid]; for (int k=0;k<10;k++) s += T1[i10*10+k]*D[j10*10+k]; Pnn[tid]=s; }
        __syncthreads();
        if (tid < 10) { dout[OUT_ZS + (b*127+t)*10 + tid] = zn[tid]; zc[tid]=zn[tid]; }
        if (tid < 100){ dout[OUT_PS + (b*127+t)*100 + tid] = Pnn[tid]; Pc[tid]=Pnn[tid]; }
    }
}

// ============================ launch ============================
extern "C" void kernel_launch(void* const* d_in, const int* in_sizes, int n_in,
                              void* d_out, int out_size, void* d_ws, size_t ws_size,
                              hipStream_t stream)
{
    (void)in_sizes; (void)n_in; (void)out_size; (void)d_ws; (void)ws_size;
    const float* images = (const float*)d_in[0];
    const float* w1   = (const float*)d_in[1];
    const float* b1   = (const float*)d_in[2];
    const float* w2   = (const float*)d_in[3];
    const float* b2   = (const float*)d_in[4];
    const float* w3   = (const float*)d_in[5];
    const float* b3   = (const float*)d_in[6];
    const float* wd   = (const float*)d_in[7];
    const float* bd   = (const float*)d_in[8];
    const float* lk   = (const float*)d_in[9];
    const float* lrk  = (const float*)d_in[10];
    const float* lb   = (const float*)d_in[11];
    const float* wabc = (const float*)d_in[12];
    const float* babc = (const float*)d_in[13];
    float* dout = (float*)d_out;   // d_out is FLOAT32 (verified R10)

    u16 *c1p, *c2p, *w2hp, *w2lp, *w3hp, *w3lp;
    float *c3p, *wdTp;
    hipGetSymbolAddress((void**)&c1p,  HIP_SYMBOL(r14_c1));
    hipGetSymbolAddress((void**)&c2p,  HIP_SYMBOL(r14_c2));
    hipGetSymbolAddress((void**)&c3p,  HIP_SYMBOL(r14_c3));
    hipGetSymbolAddress((void**)&w2hp, HIP_SYMBOL(r14_w2h));
    hipGetSymbolAddress((void**)&w2lp, HIP_SYMBOL(r14_w2l));
    hipGetSymbolAddress((void**)&w3hp, HIP_SYMBOL(r14_w3h));
    hipGetSymbolAddress((void**)&w3lp, HIP_SYMBOL(r14_w3l));
    hipGetSymbolAddress((void**)&wdTp, HIP_SYMBOL(r14_wdT));

    conv1_r14<<<dim3(384), dim3(256), 0, stream>>>(images, w1, b1, c1p);
    w2t_r14<<<dim3(512), dim3(256), 0, stream>>>(w2, w2hp, w2lp);
    w3t_r14<<<dim3(4096), dim3(256), 0, stream>>>(w3, w3hp, w3lp);
    wdt_r14<<<dim3(640), dim3(256), 0, stream>>>(wd, wdTp);
    conv2_r19<<<dim3(4, 384), dim3(256), 0, stream>>>(c1p, w2hp, w2lp, b2, c2p);
    conv3_r19<<<dim3(2, 384), dim3(256), 0, stream>>>(c2p, w3hp, w3lp, b3, c3p);
    dense_r14<<<dim3(384), dim3(256), 0, stream>>>(bd, dout);
    lstm_r14<<<dim3(3), dim3(512), 0, stream>>>(lk, lrk, lb);
    abc_r14<<<dim3(384), dim3(192), 0, stream>>>(wabc, babc, dout);
    kf_r15<<<dim3(3), dim3(128), 0, stream>>>(dout);
    ginv_r14<<<dim3(381), dim3(256), 0, stream>>>();
    rts_r14<<<dim3(3), dim3(128), 0, stream>>>(dout);
}

// Round 6
// 1101.555 us; speedup vs baseline: 1.0058x; 1.0058x over previous
//
#include <hip/hip_runtime.h>
#include <math.h>

typedef unsigned int   u32;
typedef unsigned short u16;
typedef short bf16x8 __attribute__((ext_vector_type(8)));
typedef float f32x4  __attribute__((ext_vector_type(4)));

// ---- output element offsets (d_out is FLOAT32, 101760 elements) ----
#define OUT_ZS    0
#define OUT_PS    3810
#define OUT_AALL  41910
#define OUT_A     43830
#define OUT_C     82230
#define OUT_LASTZ 101430
#define OUT_LASTP 101460

__device__ __forceinline__ float sigm(float x){ return 1.f/(1.f+expf(-x)); }
__device__ __forceinline__ float safed(float d){
    return (fabsf(d) < 1e-30f) ? ((d < 0.f) ? -1e-30f : 1e-30f) : d;
}
__device__ __forceinline__ u16 f2b(float f) {
    union { float f; u32 u; } v; v.f = f;
    u32 r = v.u + 0x7fffu + ((v.u >> 16) & 1u);   // RNE
    return (u16)(r >> 16);
}
__device__ __forceinline__ float b2f(u16 u) {
    union { u32 x; float f; } v; v.x = ((u32)u) << 16; return v.f;
}
__device__ __forceinline__ u32 packb(float a, float b){ return (u32)f2b(a) | ((u32)f2b(b) << 16); }

// ---- static device workspace ----
__device__ u16   r14_c1[25165824];   // conv1 out bf16 NHWC [384][32][32][64]
__device__ u16   r14_c2[12582912];   // conv2 out bf16 NHWC [384][16][16][128]
__device__ u16   r14_w2h[131072];    // w2T hi bf16 [128 oc][1024 k]
__device__ u16   r14_w2l[131072];    // w2T lo bf16
__device__ u16   r14_w3h[1048576];   // w3T hi bf16 [512 oc][2048 k]
__device__ u16   r14_w3l[1048576];   // w3T lo bf16
__device__ float r20_dpart[3840];    // dense partials [384 f][2 ocg][5 d]
__device__ float r14_hs[49152];
__device__ float r14_zhat[3840];
__device__ float r14_phat[38400];
__device__ float r14_pz[3840];
__device__ float r14_pp[38400];
__device__ float r14_aall[1920];
__device__ float r14_A[38400];
__device__ float r14_C[19200];
__device__ float r14_G[38400];

// ============================ conv1 (fp32 VALU, bf16 NHWC out) ============================
__global__ __launch_bounds__(256) void conv1_r14(const float* __restrict__ img,
        const float* __restrict__ w1, const float* __restrict__ b1, u16* __restrict__ out)
{
    __shared__ float in_lds[66*66];
    const int f = blockIdx.x, tid = threadIdx.x;
    const int og = tid >> 5, sg = tid & 31;

    for (int i = tid; i < 66*66; i += 256) in_lds[i] = 0.f;
    __syncthreads();
    const float4* src = (const float4*)(img + f*4096);
    for (int i = tid; i < 1024; i += 256) {
        int r = i >> 4, c0 = (i & 15) * 4;
        float4 v = src[i];
        float* dst = &in_lds[(r+1)*66 + c0 + 1];
        dst[0]=v.x; dst[1]=v.y; dst[2]=v.z; dst[3]=v.w;
    }
    float wr[16][8];
    #pragma unroll
    for (int k = 0; k < 16; k++) {
        float4 a = *(const float4*)&w1[k*64 + og*8];
        float4 b = *(const float4*)&w1[k*64 + og*8 + 4];
        wr[k][0]=a.x; wr[k][1]=a.y; wr[k][2]=a.z; wr[k][3]=a.w;
        wr[k][4]=b.x; wr[k][5]=b.y; wr[k][6]=b.z; wr[k][7]=b.w;
    }
    float bias[8];
    #pragma unroll
    for (int j = 0; j < 8; j++) bias[j] = b1[og*8+j];
    __syncthreads();

    for (int yy = 0; yy < 32; yy++) {
        float inv[16];
        #pragma unroll
        for (int ky = 0; ky < 4; ky++)
            #pragma unroll
            for (int kx = 0; kx < 4; kx++)
                inv[ky*4+kx] = in_lds[(2*yy+ky)*66 + 2*sg+kx];
        float acc[8];
        #pragma unroll
        for (int j = 0; j < 8; j++) acc[j] = bias[j];
        #pragma unroll
        for (int k = 0; k < 16; k++)
            #pragma unroll
            for (int j = 0; j < 8; j++) acc[j] += inv[k]*wr[k][j];
        #pragma unroll
        for (int j = 0; j < 8; j++) acc[j] = fmaxf(acc[j], 0.f);
        uint4 pk = make_uint4(packb(acc[0],acc[1]), packb(acc[2],acc[3]),
                              packb(acc[4],acc[5]), packb(acc[6],acc[7]));
        *(uint4*)(out + (f*1024 + yy*32 + sg)*64 + og*8) = pk;
    }
}

// ============================ weight transpose + bf16 split ============================
__global__ __launch_bounds__(256) void w2t_r14(const float* __restrict__ w2,
        u16* __restrict__ hi, u16* __restrict__ lo)
{
    int idx = blockIdx.x*256 + threadIdx.x;
    if (idx < 131072) {
        int k = idx >> 7, oc = idx & 127;
        float v = w2[idx];
        u16 h = f2b(v);
        hi[oc*1024 + k] = h;
        lo[oc*1024 + k] = f2b(v - b2f(h));
    }
}
__global__ __launch_bounds__(256) void w3t_r14(const float* __restrict__ w3,
        u16* __restrict__ hi, u16* __restrict__ lo)
{
    int idx = blockIdx.x*256 + threadIdx.x;
    if (idx < 1048576) {
        int k = idx >> 9, oc = idx & 511;
        float v = w3[idx];
        u16 h = f2b(v);
        hi[oc*2048 + k] = h;
        lo[oc*2048 + k] = f2b(v - b2f(h));
    }
}

// ============================ conv2 MFMA (r14: per-tap staging) ============================
__global__ __launch_bounds__(256) void conv2_r14(const u16* __restrict__ c1b,
        const u16* __restrict__ w2h, const u16* __restrict__ w2l,
        const float* __restrict__ b2, u16* __restrict__ c2b)
{
    __shared__ __align__(16) u16 slab[128*72];
    const int f = blockIdx.x, mc = blockIdx.y, tid = threadIdx.x;
    const int wave = tid >> 6, lane = tid & 63, quad = lane >> 4, ln = lane & 15;

    f32x4 acc[8][2];
    const f32x4 zz = {0.f, 0.f, 0.f, 0.f};
    #pragma unroll
    for (int mt = 0; mt < 8; mt++) { acc[mt][0] = zz; acc[mt][1] = zz; }

    const int sp = tid >> 1;
    const int sy = mc*8 + (sp >> 4), sx = sp & 15;
    const int sic = (tid & 1) * 32;

    for (int kk = 0; kk < 16; kk++) {
        const int ky = kk >> 2, kx = kk & 3;
        __syncthreads();
        {
            int iy = 2*sy - 1 + ky, ix = 2*sx - 1 + kx;
            uint4* d4 = (uint4*)&slab[sp*72 + sic];
            if (iy >= 0 && iy < 32 && ix >= 0 && ix < 32) {
                const uint4* s4 = (const uint4*)&c1b[((f*32 + iy)*32 + ix)*64 + sic];
                d4[0]=s4[0]; d4[1]=s4[1]; d4[2]=s4[2]; d4[3]=s4[3];
            } else {
                uint4 z = make_uint4(0,0,0,0);
                d4[0]=z; d4[1]=z; d4[2]=z; d4[3]=z;
            }
        }
        __syncthreads();
        #pragma unroll
        for (int ks = 0; ks < 2; ks++) {
            bf16x8 af[8];
            #pragma unroll
            for (int mt = 0; mt < 8; mt++)
                af[mt] = *(const bf16x8*)&slab[(mt*16 + ln)*72 + ks*32 + quad*8];
            #pragma unroll
            for (int nt = 0; nt < 2; nt++) {
                const int oc = wave*32 + nt*16 + ln;
                const int kb = kk*64 + ks*32 + quad*8;
                bf16x8 bh = *(const bf16x8*)&w2h[oc*1024 + kb];
                bf16x8 bl = *(const bf16x8*)&w2l[oc*1024 + kb];
                #pragma unroll
                for (int mt = 0; mt < 8; mt++) {
                    acc[mt][nt] = __builtin_amdgcn_mfma_f32_16x16x32_bf16(af[mt], bh, acc[mt][nt], 0,0,0);
                    acc[mt][nt] = __builtin_amdgcn_mfma_f32_16x16x32_bf16(af[mt], bl, acc[mt][nt], 0,0,0);
                }
            }
        }
    }
    #pragma unroll
    for (int nt = 0; nt < 2; nt++) {
        const int oc = wave*32 + nt*16 + ln;
        const float bias = b2[oc];
        #pragma unroll
        for (int mt = 0; mt < 8; mt++)
            #pragma unroll
            for (int r = 0; r < 4; r++) {
                int pix = mc*128 + mt*16 + quad*4 + r;
                c2b[(f*256 + pix)*128 + oc] = f2b(fmaxf(acc[mt][nt][r] + bias, 0.f));
            }
    }
}

// ============================ conv3 MFMA (r20: r14 structure + fused dense partials) ============================
// No c3 write: each thread folds its 64 relu'd outputs into 5 dense partial sums,
// block reduces in slab, writes r20_dpart[(f*2+ocg)*5 + d].
__global__ __launch_bounds__(256) void conv3_r20(const u16* __restrict__ c2b,
        const u16* __restrict__ w3h, const u16* __restrict__ w3l,
        const float* __restrict__ b3, const float* __restrict__ wd)
{
    __shared__ __align__(16) u16 slab[64*136];
    const int f = blockIdx.x, ocg = blockIdx.y, tid = threadIdx.x;
    const int wave = tid >> 6, lane = tid & 63, quad = lane >> 4, ln = lane & 15;
    const int wn = ocg*256 + wave*64;

    f32x4 acc[4][4];
    const f32x4 zz = {0.f, 0.f, 0.f, 0.f};
    #pragma unroll
    for (int mt = 0; mt < 4; mt++)
        #pragma unroll
        for (int nt = 0; nt < 4; nt++) acc[mt][nt] = zz;

    const int sp = tid >> 2;
    const int sy = sp >> 3, sx = sp & 7;
    const int sic = (tid & 3) * 32;

    for (int kk = 0; kk < 16; kk++) {
        const int ky = kk >> 2, kx = kk & 3;
        __syncthreads();
        {
            int iy = 2*sy - 1 + ky, ix = 2*sx - 1 + kx;
            uint4* d4 = (uint4*)&slab[sp*136 + sic];
            if (iy >= 0 && iy < 16 && ix >= 0 && ix < 16) {
                const uint4* s4 = (const uint4*)&c2b[((f*16 + iy)*16 + ix)*128 + sic];
                d4[0]=s4[0]; d4[1]=s4[1]; d4[2]=s4[2]; d4[3]=s4[3];
            } else {
                uint4 z = make_uint4(0,0,0,0);
                d4[0]=z; d4[1]=z; d4[2]=z; d4[3]=z;
            }
        }
        __syncthreads();
        #pragma unroll
        for (int ks = 0; ks < 4; ks++) {
            bf16x8 af[4];
            #pragma unroll
            for (int mt = 0; mt < 4; mt++)
                af[mt] = *(const bf16x8*)&slab[(mt*16 + ln)*136 + ks*32 + quad*8];
            #pragma unroll
            for (int nt = 0; nt < 4; nt++) {
                const int oc = wn + nt*16 + ln;
                const int kb = kk*128 + ks*32 + quad*8;
                bf16x8 bh = *(const bf16x8*)&w3h[oc*2048 + kb];
                bf16x8 bl = *(const bf16x8*)&w3l[oc*2048 + kb];
                #pragma unroll
                for (int mt = 0; mt < 4; mt++) {
                    acc[mt][nt] = __builtin_amdgcn_mfma_f32_16x16x32_bf16(af[mt], bh, acc[mt][nt], 0,0,0);
                    acc[mt][nt] = __builtin_amdgcn_mfma_f32_16x16x32_bf16(af[mt], bl, acc[mt][nt], 0,0,0);
                }
            }
        }
    }

    // fused dense partial sums (c3 never materialized)
    float pd0=0.f, pd1=0.f, pd2=0.f, pd3=0.f, pd4=0.f;
    #pragma unroll
    for (int nt = 0; nt < 4; nt++) {
        const int oc = wn + nt*16 + ln;
        const float bias = b3[oc];
        #pragma unroll
        for (int mt = 0; mt < 4; mt++)
            #pragma unroll
            for (int r = 0; r < 4; r++) {
                const int pix = mt*16 + quad*4 + r;
                const float v = fmaxf(acc[mt][nt][r] + bias, 0.f);
                const float* wp = &wd[(pix*512 + oc)*20];
                float4 w4 = *(const float4*)wp;     // 80B*j is 16B aligned
                pd0 += v*w4.x; pd1 += v*w4.y; pd2 += v*w4.z; pd3 += v*w4.w;
                pd4 += v*wp[4];
            }
    }
    __syncthreads();                 // done reading slab as u16
    float* red = (float*)slab;       // [5][256] floats = 5 KB < 17 KB
    red[0*256+tid]=pd0; red[1*256+tid]=pd1; red[2*256+tid]=pd2;
    red[3*256+tid]=pd3; red[4*256+tid]=pd4;
    __syncthreads();
    for (int st = 128; st > 0; st >>= 1) {
        if (tid < st) {
            #pragma unroll
            for (int d = 0; d < 5; d++) red[d*256+tid] += red[d*256+tid+st];
        }
        __syncthreads();
    }
    if (tid < 5) r20_dpart[(f*2 + ocg)*5 + tid] = red[tid*256];
}

// ============================ LSTM (r20: finalizes a_all from dense partials) ============================
__global__ __launch_bounds__(512) void lstm_r20(const float* __restrict__ lk,
        const float* __restrict__ lrk, const float* __restrict__ lb,
        const float* __restrict__ bd, float* __restrict__ dout)
{
    const int b = blockIdx.x, c = threadIdx.x;   // c = gate column 0..511
    __shared__ float a_lds[640];
    __shared__ float h_lds[128];
    __shared__ float g_lds[512];
    for (int i = c; i < 640; i += 512) {
        const int f = b*128 + i/5, d = i % 5;
        const float v = bd[d] + r20_dpart[f*10 + d] + r20_dpart[f*10 + 5 + d];
        a_lds[i] = v;
        r14_aall[f*5 + d] = v;
        dout[OUT_AALL + f*5 + d] = v;
    }
    if (c < 128) h_lds[c] = 0.f;
    float wreg[128];                    // lrk column resident in VGPRs
    #pragma unroll
    for (int j = 0; j < 128; j++) wreg[j] = lrk[j*512 + c];
    float lkr[5];
    #pragma unroll
    for (int d = 0; d < 5; d++) lkr[d] = lk[d*512 + c];
    const float gb = lb[c];
    float cs = 0.f;
    __syncthreads();
    for (int t = 0; t < 128; t++) {
        float g = gb;
        if (t > 0) {
            #pragma unroll
            for (int d = 0; d < 5; d++) g += a_lds[(t-1)*5 + d] * lkr[d];
        }
        float s0=0.f, s1=0.f, s2=0.f, s3=0.f;   // 4 chains to break fp-add dependence
        #pragma unroll
        for (int j = 0; j < 128; j += 4) {
            float4 h4 = *(const float4*)&h_lds[j];
            s0 += h4.x*wreg[j];   s1 += h4.y*wreg[j+1];
            s2 += h4.z*wreg[j+2]; s3 += h4.w*wreg[j+3];
        }
        g += (s0 + s1) + (s2 + s3);
        g_lds[c] = g;
        __syncthreads();
        if (c < 128) {
            float gi = g_lds[c], gf = g_lds[c+128], gg = g_lds[c+256], go = g_lds[c+384];
            cs = sigm(gf)*cs + sigm(gi)*tanhf(gg);
            float hn = sigm(go)*tanhf(cs);
            h_lds[c] = hn;
            r14_hs[(t*3 + b)*128 + c] = hn;
        }
        __syncthreads();
    }
}

// ============================ abc -> A, C ============================
__global__ __launch_bounds__(192) void abc_r14(const float* __restrict__ wabc,
        const float* __restrict__ babc, float* __restrict__ dout)
{
    const int tb = blockIdx.x, c = threadIdx.x;
    __shared__ float h_lds[128];
    if (c < 128) h_lds[c] = r14_hs[tb*128 + c];
    __syncthreads();
    if (c < 150) {
        float s = babc[c];
        for (int j = 0; j < 128; j++) s += h_lds[j]*wabc[j*150 + c];
        if (c < 100) { r14_A[tb*100 + c] = s; dout[OUT_A + tb*100 + c] = s; }
        else         { r14_C[tb*50 + (c-100)] = s; dout[OUT_C + tb*50 + (c-100)] = s; }
    }
}

// ============================ Kalman filter (r20: single-wave, 6 phases, prefetch) ============================
// 64 threads: lane covers elements tid and tid+64. Per-element arithmetic identical to r15.
__global__ __launch_bounds__(64) void kf_r20(float* __restrict__ dout)
{
    const int b = blockIdx.x, tid = threadIdx.x;
    const int e1 = tid + 64;
    const int i0 = tid/10, j0 = tid%10;
    const int i1 = e1/10, j1 = e1%10;
    const bool h1 = (tid < 36);                 // e1 < 100
    const bool hz = (tid >= 36 && tid < 46);    // zh/pz slot
    const int zi = tid - 36;
    __shared__ float Ab[2][100], Cb[2][56], avb[2][8];
    __shared__ float z[12], P[100], zh[12], AP[100], Ph[100], resid[8],
                     CPm[52], PCt[52], Ssh[28], Kg[52];

    float rA0 = 0.f, rA1 = 0.f, rC = 0.f, rav = 0.f;
    // stage t=0
    rA0 = r14_A[b*100 + tid];
    if (h1)      rA1 = r14_A[b*100 + e1];
    if (tid<50)  rC  = r14_C[b*50 + tid];
    if (tid<5)   rav = r14_aall[(b*128+0)*5 + tid];
    P[tid] = (i0==j0) ? 1.f : 0.f;
    if (h1) P[e1] = (i1==j1) ? 1.f : 0.f;
    if (tid < 10) z[tid] = 0.f;
    Ab[0][tid] = rA0;
    if (h1)     Ab[0][e1] = rA1;
    if (tid<50) Cb[0][tid] = rC;
    if (tid<5)  avb[0][tid] = rav;
    // prefetch t=1
    rA0 = r14_A[(3+b)*100 + tid];
    if (h1)      rA1 = r14_A[(3+b)*100 + e1];
    if (tid<50)  rC  = r14_C[(3+b)*50 + tid];
    if (tid<5)   rav = r14_aall[(b*128+1)*5 + tid];
    __syncthreads();

    for (int t = 0; t < 128; t++) {
        const int cb = t & 1, nb = cb ^ 1;
        const float* Ax = Ab[cb];
        const float* Cx = Cb[cb];

        // P1: AP = A@P  ||  zh = A@z
        {
            float s = 0.f;
            #pragma unroll
            for (int k = 0; k < 10; k++) s += Ax[i0*10+k]*P[k*10+j0];
            AP[tid] = s;
            if (h1) {
                float s1 = 0.f;
                #pragma unroll
                for (int k = 0; k < 10; k++) s1 += Ax[i1*10+k]*P[k*10+j1];
                AP[e1] = s1;
            }
            if (hz) {
                float s2 = 0.f;
                #pragma unroll
                for (int k = 0; k < 10; k++) s2 += Ax[zi*10+k]*z[k];
                zh[zi] = s2;
            }
        }
        __syncthreads();

        // P2: Ph = AP@A^T + Q  ||  resid = a - C@zh
        {
            float s = (i0==j0) ? 0.08f : 0.f;
            #pragma unroll
            for (int k = 0; k < 10; k++) s += AP[i0*10+k]*Ax[j0*10+k];
            Ph[tid] = s;
            if (h1) {
                float s1 = (i1==j1) ? 0.08f : 0.f;
                #pragma unroll
                for (int k = 0; k < 10; k++) s1 += AP[i1*10+k]*Ax[j1*10+k];
                Ph[e1] = s1;
            }
            if (tid >= 36 && tid < 41) {
                const int c = tid - 36;
                float s2 = avb[cb][c];
                #pragma unroll
                for (int k = 0; k < 10; k++) s2 -= Cx[c*10+k]*zh[k];
                resid[c] = s2;
            }
        }
        __syncthreads();

        // P3: CPm = C@Ph (lanes 0-49)  ||  PCt = Ph@C^T (lanes 50-63 q0-13, lanes 0-35 q14-49)
        {
            if (tid < 50) {
                const int i = tid/10, j = tid%10;
                float s = 0.f;
                #pragma unroll
                for (int k = 0; k < 10; k++) s += Cx[i*10+k]*Ph[k*10+j];
                CPm[tid] = s;
            } else {
                const int q = tid - 50, i = q/5, j = q%5;
                float s = 0.f;
                #pragma unroll
                for (int k = 0; k < 10; k++) s += Ph[i*10+k]*Cx[j*10+k];
                PCt[q] = s;
            }
            if (h1) {
                const int q = tid + 14, i = q/5, j = q%5;
                float s = 0.f;
                #pragma unroll
                for (int k = 0; k < 10; k++) s += Ph[i*10+k]*Cx[j*10+k];
                PCt[q] = s;
            }
        }
        __syncthreads();

        // P4: S = CPm@C^T + R (lanes 0-24)
        if (tid < 25) {
            const int i = tid/5, j = tid%5;
            float s = (i==j) ? 0.03f : 0.f;
            #pragma unroll
            for (int k = 0; k < 10; k++) s += CPm[i*10+k]*Cx[j*10+k];
            Ssh[tid] = s;
        }
        __syncthreads();

        // P5: lanes 0-9 solve S^T y = PCt[i,:]^T in registers -> K row i
        if (tid < 10) {
            float M[5][5], bb[5], pv[5], x[5];
            #pragma unroll
            for (int r = 0; r < 5; r++)
                #pragma unroll
                for (int c = 0; c < 5; c++) M[r][c] = Ssh[c*5+r];   // M = S^T
            #pragma unroll
            for (int k = 0; k < 5; k++) bb[k] = PCt[tid*5+k];
            #pragma unroll
            for (int k = 0; k < 5; k++) {
                const float p = 1.f/safed(M[k][k]);
                pv[k] = p;
                #pragma unroll
                for (int r = k+1; r < 5; r++) {
                    const float f = M[r][k]*p;
                    #pragma unroll
                    for (int c = k+1; c < 5; c++) M[r][c] -= f*M[k][c];
                    bb[r] -= f*bb[k];
                }
            }
            #pragma unroll
            for (int k = 4; k >= 0; k--) {
                float s = bb[k];
                #pragma unroll
                for (int c = k+1; c < 5; c++) s -= M[k][c]*x[c];
                x[k] = s*pv[k];
            }
            #pragma unroll
            for (int k = 0; k < 5; k++) Kg[tid*5+k] = x[k];
        }
        __syncthreads();

        // P6: Pn, pz, stores, staging+prefetch
        {
            float s = Ph[tid];
            #pragma unroll
            for (int k = 0; k < 5; k++) s -= Kg[i0*5+k]*CPm[k*10+j0];
            r14_pp[(t*3+b)*100 + tid] = s;
            P[tid] = s;
            r14_phat[(t*3+b)*100 + tid] = fmaxf(Ph[tid], (i0==j0)?1e-4f:0.f);
            if (tid < 10) r14_zhat[(t*3+b)*10 + tid] = zh[tid];
            if (h1) {
                float s1 = Ph[e1];
                #pragma unroll
                for (int k = 0; k < 5; k++) s1 -= Kg[i1*5+k]*CPm[k*10+j1];
                r14_pp[(t*3+b)*100 + e1] = s1;
                P[e1] = s1;
                r14_phat[(t*3+b)*100 + e1] = fmaxf(Ph[e1], (i1==j1)?1e-4f:0.f);
            }
            if (hz) {
                float s2 = zh[zi];
                #pragma unroll
                for (int k = 0; k < 5; k++) s2 += Kg[zi*5+k]*resid[k];
                r14_pz[(t*3+b)*10 + zi] = s2;
                z[zi] = s2;
            }
            if (t < 127) {
                Ab[nb][tid] = rA0;
                if (h1)     Ab[nb][e1] = rA1;
                if (tid<50) Cb[nb][tid] = rC;
                if (tid<5)  avb[nb][tid] = rav;
                if (t < 126) {
                    rA0 = r14_A[((t+2)*3+b)*100 + tid];
                    if (h1)      rA1 = r14_A[((t+2)*3+b)*100 + e1];
                    if (tid<50)  rC  = r14_C[((t+2)*3+b)*50 + tid];
                    if (tid<5)   rav = r14_aall[(b*128+(t+2))*5 + tid];
                }
            }
        }
        __syncthreads();
    }
    if (tid < 10) dout[OUT_LASTZ + b*10 + tid] = z[tid];
    dout[OUT_LASTP + b*100 + tid] = P[tid];
    if (h1) dout[OUT_LASTP + b*100 + e1] = P[e1];
}

// ============================ G = A^T @ inv(Phat_clamped) ============================
__global__ __launch_bounds__(256) void ginv_r14()
{
    const int idx = blockIdx.x;
    const int tt = idx/3 + 1, b = idx%3;
    const int tid = threadIdx.x;
    __shared__ float M[10][21];
    __shared__ float A[100];
    __shared__ int piv;
    if (tid < 100) {
        int i = tid/10, j = tid%10;
        M[i][j] = r14_phat[(tt*3+b)*100 + tid];
        M[i][10+j] = (i==j) ? 1.f : 0.f;
        A[tid] = r14_A[(tt*3+b)*100 + tid];
    }
    __syncthreads();
    const int r = tid/20, cc = tid%20;
    for (int k = 0; k < 10; k++) {
        if (tid == 0) {
            int p = k; float best = fabsf(M[k][k]);
            for (int rr = k+1; rr < 10; rr++) {
                float v = fabsf(M[rr][k]);
                if (v > best) { best = v; p = rr; }
            }
            piv = p;
        }
        __syncthreads();
        if (piv != k && tid < 20) {
            float a = M[k][tid], bb = M[piv][tid];
            M[k][tid] = bb; M[piv][tid] = a;
        }
        __syncthreads();
        float pinv = 1.f/safed(M[k][k]);
        float myf = 0.f, rowv = 0.f;
        if (tid < 200) { myf = M[r][k]; rowv = M[k][cc]; }
        __syncthreads();
        if (tid < 200) {
            if (r == k) M[k][cc] = rowv*pinv;
            else        M[r][cc] -= myf*pinv*rowv;
        }
        __syncthreads();
    }
    if (tid < 100) {
        int i = tid/10, j = tid%10;
        float s = 0.f;
        #pragma unroll
        for (int k = 0; k < 10; k++) s += A[k*10+i]*M[k][10+j];
        r14_G[(tt*3+b)*100 + tid] = s;
    }
}

// ============================ RTS smoother (r20: single-wave, 3 phases, prefetch) ============================
// step t data: Gt=G[(t+1)], pPm=pp[t], ph=phat[(t+1)], zh=zhat[(t+1)], pzv=pz[t]
__global__ __launch_bounds__(64) void rts_r20(float* __restrict__ dout)
{
    const int b = blockIdx.x, tid = threadIdx.x;
    const int e1 = tid + 64;
    const int i0 = tid/10, j0 = tid%10;
    const int i1 = e1/10, j1 = e1%10;
    const bool h1 = (tid < 36);
    const bool hz = (tid >= 36 && tid < 46);
    const int zi = tid - 36;
    __shared__ float zc[12], Pc[100], D[100], dz[12], T1[100];
    __shared__ float Gtb[2][100], pPb[2][100], phb[2][100], zhb[2][12], pzb[2][12];

    // carry init
    if (tid < 10) zc[tid] = r14_pz[(127*3+b)*10 + tid];
    Pc[tid] = r14_pp[(127*3+b)*100 + tid];
    if (h1) Pc[e1] = r14_pp[(127*3+b)*100 + e1];

    float g0=0.f, g1=0.f, p0=0.f, p1=0.f, f0=0.f, f1=0.f, zr=0.f, pr=0.f;
    // stage t=126 into buf0
    Gtb[0][tid] = r14_G[(127*3+b)*100 + tid];
    pPb[0][tid] = r14_pp[(126*3+b)*100 + tid];
    phb[0][tid] = r14_phat[(127*3+b)*100 + tid];
    if (h1) {
        Gtb[0][e1] = r14_G[(127*3+b)*100 + e1];
        pPb[0][e1] = r14_pp[(126*3+b)*100 + e1];
        phb[0][e1] = r14_phat[(127*3+b)*100 + e1];
    }
    if (hz) {
        zhb[0][zi] = r14_zhat[(127*3+b)*10 + zi];
        pzb[0][zi] = r14_pz[(126*3+b)*10 + zi];
    }
    // prefetch t=125 into regs
    g0 = r14_G[(126*3+b)*100 + tid];
    p0 = r14_pp[(125*3+b)*100 + tid];
    f0 = r14_phat[(126*3+b)*100 + tid];
    if (h1) {
        g1 = r14_G[(126*3+b)*100 + e1];
        p1 = r14_pp[(125*3+b)*100 + e1];
        f1 = r14_phat[(126*3+b)*100 + e1];
    }
    if (hz) {
        zr = r14_zhat[(126*3+b)*10 + zi];
        pr = r14_pz[(125*3+b)*10 + zi];
    }
    __syncthreads();

    for (int t = 126; t >= 0; t--) {
        const int cb = (126 - t) & 1, nb = cb ^ 1;

        // P1: D = pPm @ Gt  ||  dz = zc - zh
        {
            float s = 0.f;
            #pragma unroll
            for (int k = 0; k < 10; k++) s += pPb[cb][i0*10+k]*Gtb[cb][k*10+j0];
            D[tid] = s;
            if (h1) {
                float s1 = 0.f;
                #pragma unroll
                for (int k = 0; k < 10; k++) s1 += pPb[cb][i1*10+k]*Gtb[cb][k*10+j1];
                D[e1] = s1;
            }
            if (hz) dz[zi] = zc[zi] - zhb[cb][zi];
        }
        __syncthreads();

        // P2: T1 = D @ (Pc - ph)  ||  zn = pzv + D@dz (write zc + dout)
        {
            float s = 0.f;
            #pragma unroll
            for (int k = 0; k < 10; k++) s += D[i0*10+k]*(Pc[k*10+j0] - phb[cb][k*10+j0]);
            T1[tid] = s;
            if (h1) {
                float s1 = 0.f;
                #pragma unroll
                for (int k = 0; k < 10; k++) s1 += D[i1*10+k]*(Pc[k*10+j1] - phb[cb][k*10+j1]);
                T1[e1] = s1;
            }
            if (hz) {
                float s2 = pzb[cb][zi];
                #pragma unroll
                for (int k = 0; k < 10; k++) s2 += D[zi*10+k]*dz[k];
                zc[zi] = s2;
                dout[OUT_ZS + (b*127+t)*10 + zi] = s2;
            }
        }
        __syncthreads();

        // P3: Pnn = pPm + T1@D^T (write Pc + dout) + staging/prefetch
        {
            float s = pPb[cb][tid];
            #pragma unroll
            for (int k = 0; k < 10; k++) s += T1[i0*10+k]*D[j0*10+k];
            dout[OUT_PS + (b*127+t)*100 + tid] = s;
            Pc[tid] = s;
            if (h1) {
                float s1 = pPb[cb][e1];
                #pragma unroll
                for (int k = 0; k < 10; k++) s1 += T1[i1*10+k]*D[j1*10+k];
                dout[OUT_PS + (b*127+t)*100 + e1] = s1;
                Pc[e1] = s1;
            }
            if (t > 0) {
                Gtb[nb][tid] = g0; pPb[nb][tid] = p0; phb[nb][tid] = f0;
                if (h1) { Gtb[nb][e1] = g1; pPb[nb][e1] = p1; phb[nb][e1] = f1; }
                if (hz) { zhb[nb][zi] = zr; pzb[nb][zi] = pr; }
                if (t > 1) {
                    const int s2 = t - 2;
                    g0 = r14_G[((s2+1)*3+b)*100 + tid];
                    p0 = r14_pp[(s2*3+b)*100 + tid];
                    f0 = r14_phat[((s2+1)*3+b)*100 + tid];
                    if (h1) {
                        g1 = r14_G[((s2+1)*3+b)*100 + e1];
                        p1 = r14_pp[(s2*3+b)*100 + e1];
                        f1 = r14_phat[((s2+1)*3+b)*100 + e1];
                    }
                    if (hz) {
                        zr = r14_zhat[((s2+1)*3+b)*10 + zi];
                        pr = r14_pz[(s2*3+b)*10 + zi];
                    }
                }
            }
        }
        __syncthreads();
    }
}

// ============================ launch ============================
extern "C" void kernel_launch(void* const* d_in, const int* in_sizes, int n_in,
                              void* d_out, int out_size, void* d_ws, size_t ws_size,
                              hipStream_t stream)
{
    (void)in_sizes; (void)n_in; (void)out_size; (void)d_ws; (void)ws_size;
    const float* images = (const float*)d_in[0];
    const float* w1   = (const float*)d_in[1];
    const float* b1   = (const float*)d_in[2];
    const float* w2   = (const float*)d_in[3];
    const float* b2   = (const float*)d_in[4];
    const float* w3   = (const float*)d_in[5];
    const float* b3   = (const float*)d_in[6];
    const float* wd   = (const float*)d_in[7];
    const float* bd   = (const float*)d_in[8];
    const float* lk   = (const float*)d_in[9];
    const float* lrk  = (const float*)d_in[10];
    const float* lb   = (const float*)d_in[11];
    const float* wabc = (const float*)d_in[12];
    const float* babc = (const float*)d_in[13];
    float* dout = (float*)d_out;   // d_out is FLOAT32 (verified R10)

    u16 *c1p, *c2p, *w2hp, *w2lp, *w3hp, *w3lp;
    hipGetSymbolAddress((void**)&c1p,  HIP_SYMBOL(r14_c1));
    hipGetSymbolAddress((void**)&c2p,  HIP_SYMBOL(r14_c2));
    hipGetSymbolAddress((void**)&w2hp, HIP_SYMBOL(r14_w2h));
    hipGetSymbolAddress((void**)&w2lp, HIP_SYMBOL(r14_w2l));
    hipGetSymbolAddress((void**)&w3hp, HIP_SYMBOL(r14_w3h));
    hipGetSymbolAddress((void**)&w3lp, HIP_SYMBOL(r14_w3l));

    conv1_r14<<<dim3(384), dim3(256), 0, stream>>>(images, w1, b1, c1p);
    w2t_r14<<<dim3(512), dim3(256), 0, stream>>>(w2, w2hp, w2lp);
    w3t_r14<<<dim3(4096), dim3(256), 0, stream>>>(w3, w3hp, w3lp);
    conv2_r14<<<dim3(384, 2), dim3(256), 0, stream>>>(c1p, w2hp, w2lp, b2, c2p);
    conv3_r20<<<dim3(384, 2), dim3(256), 0, stream>>>(c2p, w3hp, w3lp, b3, wd);
    lstm_r20<<<dim3(3), dim3(512), 0, stream>>>(lk, lrk, lb, bd, dout);
    abc_r14<<<dim3(384), dim3(192), 0, stream>>>(wabc, babc, dout);
    kf_r20<<<dim3(3), dim3(64), 0, stream>>>(dout);
    ginv_r14<<<dim3(381), dim3(256), 0, stream>>>();
    rts_r20<<<dim3(3), dim3(64), 0, stream>>>(dout);
}

// Round 7
// 1036.220 us; speedup vs baseline: 1.0693x; 1.0631x over previous
//
#include <hip/hip_runtime.h>
#include <math.h>

typedef unsigned int   u32;
typedef unsigned short u16;
typedef short bf16x8 __attribute__((ext_vector_type(8)));
typedef float f32x4  __attribute__((ext_vector_type(4)));

// ---- output element offsets (d_out is FLOAT32, 101760 elements) ----
#define OUT_ZS    0
#define OUT_PS    3810
#define OUT_AALL  41910
#define OUT_A     43830
#define OUT_C     82230
#define OUT_LASTZ 101430
#define OUT_LASTP 101460

__device__ __forceinline__ float sigm(float x){ return 1.f/(1.f+expf(-x)); }
__device__ __forceinline__ float safed(float d){
    return (fabsf(d) < 1e-30f) ? ((d < 0.f) ? -1e-30f : 1e-30f) : d;
}
__device__ __forceinline__ u16 f2b(float f) {
    union { float f; u32 u; } v; v.f = f;
    u32 r = v.u + 0x7fffu + ((v.u >> 16) & 1u);   // RNE
    return (u16)(r >> 16);
}
__device__ __forceinline__ float b2f(u16 u) {
    union { u32 x; float f; } v; v.x = ((u32)u) << 16; return v.f;
}
__device__ __forceinline__ u32 packb(float a, float b){ return (u32)f2b(a) | ((u32)f2b(b) << 16); }

// ---- static device workspace ----
__device__ u16   r14_c1[25165824];   // conv1 out bf16 NHWC [384][32][32][64]
__device__ u16   r14_c2[12582912];   // conv2 out bf16 NHWC [384][16][16][128]
__device__ u16   r14_w2h[131072];    // w2T hi bf16 [128 oc][1024 k]
__device__ u16   r14_w2l[131072];    // w2T lo bf16
__device__ u16   r14_w3h[1048576];   // w3T hi bf16 [512 oc][2048 k]
__device__ u16   r14_w3l[1048576];   // w3T lo bf16
__device__ float r20_dpart[3840];    // dense partials [384 f][2 ocg][5 d]
__device__ float r14_hs[49152];
__device__ float r14_zhat[3840];
__device__ float r14_phat[38400];
__device__ float r14_pz[3840];
__device__ float r14_pp[38400];
__device__ float r14_aall[1920];
__device__ float r14_A[38400];
__device__ float r14_C[19200];
__device__ float r14_G[38400];

// ============================ conv1 (fp32 VALU, bf16 NHWC out) ============================
__global__ __launch_bounds__(256) void conv1_r14(const float* __restrict__ img,
        const float* __restrict__ w1, const float* __restrict__ b1, u16* __restrict__ out)
{
    __shared__ float in_lds[66*66];
    const int f = blockIdx.x, tid = threadIdx.x;
    const int og = tid >> 5, sg = tid & 31;

    for (int i = tid; i < 66*66; i += 256) in_lds[i] = 0.f;
    __syncthreads();
    const float4* src = (const float4*)(img + f*4096);
    for (int i = tid; i < 1024; i += 256) {
        int r = i >> 4, c0 = (i & 15) * 4;
        float4 v = src[i];
        float* dst = &in_lds[(r+1)*66 + c0 + 1];
        dst[0]=v.x; dst[1]=v.y; dst[2]=v.z; dst[3]=v.w;
    }
    float wr[16][8];
    #pragma unroll
    for (int k = 0; k < 16; k++) {
        float4 a = *(const float4*)&w1[k*64 + og*8];
        float4 b = *(const float4*)&w1[k*64 + og*8 + 4];
        wr[k][0]=a.x; wr[k][1]=a.y; wr[k][2]=a.z; wr[k][3]=a.w;
        wr[k][4]=b.x; wr[k][5]=b.y; wr[k][6]=b.z; wr[k][7]=b.w;
    }
    float bias[8];
    #pragma unroll
    for (int j = 0; j < 8; j++) bias[j] = b1[og*8+j];
    __syncthreads();

    for (int yy = 0; yy < 32; yy++) {
        float inv[16];
        #pragma unroll
        for (int ky = 0; ky < 4; ky++)
            #pragma unroll
            for (int kx = 0; kx < 4; kx++)
                inv[ky*4+kx] = in_lds[(2*yy+ky)*66 + 2*sg+kx];
        float acc[8];
        #pragma unroll
        for (int j = 0; j < 8; j++) acc[j] = bias[j];
        #pragma unroll
        for (int k = 0; k < 16; k++)
            #pragma unroll
            for (int j = 0; j < 8; j++) acc[j] += inv[k]*wr[k][j];
        #pragma unroll
        for (int j = 0; j < 8; j++) acc[j] = fmaxf(acc[j], 0.f);
        uint4 pk = make_uint4(packb(acc[0],acc[1]), packb(acc[2],acc[3]),
                              packb(acc[4],acc[5]), packb(acc[6],acc[7]));
        *(uint4*)(out + (f*1024 + yy*32 + sg)*64 + og*8) = pk;
    }
}

// ============================ weight transpose + bf16 split ============================
__global__ __launch_bounds__(256) void w2t_r14(const float* __restrict__ w2,
        u16* __restrict__ hi, u16* __restrict__ lo)
{
    int idx = blockIdx.x*256 + threadIdx.x;
    if (idx < 131072) {
        int k = idx >> 7, oc = idx & 127;
        float v = w2[idx];
        u16 h = f2b(v);
        hi[oc*1024 + k] = h;
        lo[oc*1024 + k] = f2b(v - b2f(h));
    }
}
__global__ __launch_bounds__(256) void w3t_r14(const float* __restrict__ w3,
        u16* __restrict__ hi, u16* __restrict__ lo)
{
    int idx = blockIdx.x*256 + threadIdx.x;
    if (idx < 1048576) {
        int k = idx >> 9, oc = idx & 511;
        float v = w3[idx];
        u16 h = f2b(v);
        hi[oc*2048 + k] = h;
        lo[oc*2048 + k] = f2b(v - b2f(h));
    }
}

// ============================ conv2 MFMA (r14: per-tap staging) ============================
__global__ __launch_bounds__(256) void conv2_r14(const u16* __restrict__ c1b,
        const u16* __restrict__ w2h, const u16* __restrict__ w2l,
        const float* __restrict__ b2, u16* __restrict__ c2b)
{
    __shared__ __align__(16) u16 slab[128*72];
    const int f = blockIdx.x, mc = blockIdx.y, tid = threadIdx.x;
    const int wave = tid >> 6, lane = tid & 63, quad = lane >> 4, ln = lane & 15;

    f32x4 acc[8][2];
    const f32x4 zz = {0.f, 0.f, 0.f, 0.f};
    #pragma unroll
    for (int mt = 0; mt < 8; mt++) { acc[mt][0] = zz; acc[mt][1] = zz; }

    const int sp = tid >> 1;
    const int sy = mc*8 + (sp >> 4), sx = sp & 15;
    const int sic = (tid & 1) * 32;

    for (int kk = 0; kk < 16; kk++) {
        const int ky = kk >> 2, kx = kk & 3;
        __syncthreads();
        {
            int iy = 2*sy - 1 + ky, ix = 2*sx - 1 + kx;
            uint4* d4 = (uint4*)&slab[sp*72 + sic];
            if (iy >= 0 && iy < 32 && ix >= 0 && ix < 32) {
                const uint4* s4 = (const uint4*)&c1b[((f*32 + iy)*32 + ix)*64 + sic];
                d4[0]=s4[0]; d4[1]=s4[1]; d4[2]=s4[2]; d4[3]=s4[3];
            } else {
                uint4 z = make_uint4(0,0,0,0);
                d4[0]=z; d4[1]=z; d4[2]=z; d4[3]=z;
            }
        }
        __syncthreads();
        #pragma unroll
        for (int ks = 0; ks < 2; ks++) {
            bf16x8 af[8];
            #pragma unroll
            for (int mt = 0; mt < 8; mt++)
                af[mt] = *(const bf16x8*)&slab[(mt*16 + ln)*72 + ks*32 + quad*8];
            #pragma unroll
            for (int nt = 0; nt < 2; nt++) {
                const int oc = wave*32 + nt*16 + ln;
                const int kb = kk*64 + ks*32 + quad*8;
                bf16x8 bh = *(const bf16x8*)&w2h[oc*1024 + kb];
                bf16x8 bl = *(const bf16x8*)&w2l[oc*1024 + kb];
                #pragma unroll
                for (int mt = 0; mt < 8; mt++) {
                    acc[mt][nt] = __builtin_amdgcn_mfma_f32_16x16x32_bf16(af[mt], bh, acc[mt][nt], 0,0,0);
                    acc[mt][nt] = __builtin_amdgcn_mfma_f32_16x16x32_bf16(af[mt], bl, acc[mt][nt], 0,0,0);
                }
            }
        }
    }
    #pragma unroll
    for (int nt = 0; nt < 2; nt++) {
        const int oc = wave*32 + nt*16 + ln;
        const float bias = b2[oc];
        #pragma unroll
        for (int mt = 0; mt < 8; mt++)
            #pragma unroll
            for (int r = 0; r < 4; r++) {
                int pix = mc*128 + mt*16 + quad*4 + r;
                c2b[(f*256 + pix)*128 + oc] = f2b(fmaxf(acc[mt][nt][r] + bias, 0.f));
            }
    }
}

// ============================ conv3 MFMA (r20: r14 structure + fused dense partials) ============================
__global__ __launch_bounds__(256) void conv3_r20(const u16* __restrict__ c2b,
        const u16* __restrict__ w3h, const u16* __restrict__ w3l,
        const float* __restrict__ b3, const float* __restrict__ wd)
{
    __shared__ __align__(16) u16 slab[64*136];
    const int f = blockIdx.x, ocg = blockIdx.y, tid = threadIdx.x;
    const int wave = tid >> 6, lane = tid & 63, quad = lane >> 4, ln = lane & 15;
    const int wn = ocg*256 + wave*64;

    f32x4 acc[4][4];
    const f32x4 zz = {0.f, 0.f, 0.f, 0.f};
    #pragma unroll
    for (int mt = 0; mt < 4; mt++)
        #pragma unroll
        for (int nt = 0; nt < 4; nt++) acc[mt][nt] = zz;

    const int sp = tid >> 2;
    const int sy = sp >> 3, sx = sp & 7;
    const int sic = (tid & 3) * 32;

    for (int kk = 0; kk < 16; kk++) {
        const int ky = kk >> 2, kx = kk & 3;
        __syncthreads();
        {
            int iy = 2*sy - 1 + ky, ix = 2*sx - 1 + kx;
            uint4* d4 = (uint4*)&slab[sp*136 + sic];
            if (iy >= 0 && iy < 16 && ix >= 0 && ix < 16) {
                const uint4* s4 = (const uint4*)&c2b[((f*16 + iy)*16 + ix)*128 + sic];
                d4[0]=s4[0]; d4[1]=s4[1]; d4[2]=s4[2]; d4[3]=s4[3];
            } else {
                uint4 z = make_uint4(0,0,0,0);
                d4[0]=z; d4[1]=z; d4[2]=z; d4[3]=z;
            }
        }
        __syncthreads();
        #pragma unroll
        for (int ks = 0; ks < 4; ks++) {
            bf16x8 af[4];
            #pragma unroll
            for (int mt = 0; mt < 4; mt++)
                af[mt] = *(const bf16x8*)&slab[(mt*16 + ln)*136 + ks*32 + quad*8];
            #pragma unroll
            for (int nt = 0; nt < 4; nt++) {
                const int oc = wn + nt*16 + ln;
                const int kb = kk*128 + ks*32 + quad*8;
                bf16x8 bh = *(const bf16x8*)&w3h[oc*2048 + kb];
                bf16x8 bl = *(const bf16x8*)&w3l[oc*2048 + kb];
                #pragma unroll
                for (int mt = 0; mt < 4; mt++) {
                    acc[mt][nt] = __builtin_amdgcn_mfma_f32_16x16x32_bf16(af[mt], bh, acc[mt][nt], 0,0,0);
                    acc[mt][nt] = __builtin_amdgcn_mfma_f32_16x16x32_bf16(af[mt], bl, acc[mt][nt], 0,0,0);
                }
            }
        }
    }

    // fused dense partial sums (c3 never materialized)
    float pd0=0.f, pd1=0.f, pd2=0.f, pd3=0.f, pd4=0.f;
    #pragma unroll
    for (int nt = 0; nt < 4; nt++) {
        const int oc = wn + nt*16 + ln;
        const float bias = b3[oc];
        #pragma unroll
        for (int mt = 0; mt < 4; mt++)
            #pragma unroll
            for (int r = 0; r < 4; r++) {
                const int pix = mt*16 + quad*4 + r;
                const float v = fmaxf(acc[mt][nt][r] + bias, 0.f);
                const float* wp = &wd[(pix*512 + oc)*20];
                float4 w4 = *(const float4*)wp;
                pd0 += v*w4.x; pd1 += v*w4.y; pd2 += v*w4.z; pd3 += v*w4.w;
                pd4 += v*wp[4];
            }
    }
    __syncthreads();                 // done reading slab as u16
    float* red = (float*)slab;       // [5][256] floats = 5 KB < 17 KB
    red[0*256+tid]=pd0; red[1*256+tid]=pd1; red[2*256+tid]=pd2;
    red[3*256+tid]=pd3; red[4*256+tid]=pd4;
    __syncthreads();
    for (int st = 128; st > 0; st >>= 1) {
        if (tid < st) {
            #pragma unroll
            for (int d = 0; d < 5; d++) red[d*256+tid] += red[d*256+tid+st];
        }
        __syncthreads();
    }
    if (tid < 5) r20_dpart[(f*2 + ocg)*5 + tid] = red[tid*256];
}

// ============================ LSTM (r20: finalizes a_all from dense partials) ============================
__global__ __launch_bounds__(512) void lstm_r20(const float* __restrict__ lk,
        const float* __restrict__ lrk, const float* __restrict__ lb,
        const float* __restrict__ bd, float* __restrict__ dout)
{
    const int b = blockIdx.x, c = threadIdx.x;   // c = gate column 0..511
    __shared__ float a_lds[640];
    __shared__ float h_lds[128];
    __shared__ float g_lds[512];
    for (int i = c; i < 640; i += 512) {
        const int f = b*128 + i/5, d = i % 5;
        const float v = bd[d] + r20_dpart[f*10 + d] + r20_dpart[f*10 + 5 + d];
        a_lds[i] = v;
        r14_aall[f*5 + d] = v;
        dout[OUT_AALL + f*5 + d] = v;
    }
    if (c < 128) h_lds[c] = 0.f;
    float wreg[128];                    // lrk column resident in VGPRs
    #pragma unroll
    for (int j = 0; j < 128; j++) wreg[j] = lrk[j*512 + c];
    float lkr[5];
    #pragma unroll
    for (int d = 0; d < 5; d++) lkr[d] = lk[d*512 + c];
    const float gb = lb[c];
    float cs = 0.f;
    __syncthreads();
    for (int t = 0; t < 128; t++) {
        float g = gb;
        if (t > 0) {
            #pragma unroll
            for (int d = 0; d < 5; d++) g += a_lds[(t-1)*5 + d] * lkr[d];
        }
        float s0=0.f, s1=0.f, s2=0.f, s3=0.f;   // 4 chains to break fp-add dependence
        #pragma unroll
        for (int j = 0; j < 128; j += 4) {
            float4 h4 = *(const float4*)&h_lds[j];
            s0 += h4.x*wreg[j];   s1 += h4.y*wreg[j+1];
            s2 += h4.z*wreg[j+2]; s3 += h4.w*wreg[j+3];
        }
        g += (s0 + s1) + (s2 + s3);
        g_lds[c] = g;
        __syncthreads();
        if (c < 128) {
            float gi = g_lds[c], gf = g_lds[c+128], gg = g_lds[c+256], go = g_lds[c+384];
            cs = sigm(gf)*cs + sigm(gi)*tanhf(gg);
            float hn = sigm(go)*tanhf(cs);
            h_lds[c] = hn;
            r14_hs[(t*3 + b)*128 + c] = hn;
        }
        __syncthreads();
    }
}

// ============================ abc -> A, C ============================
__global__ __launch_bounds__(192) void abc_r14(const float* __restrict__ wabc,
        const float* __restrict__ babc, float* __restrict__ dout)
{
    const int tb = blockIdx.x, c = threadIdx.x;
    __shared__ float h_lds[128];
    if (c < 128) h_lds[c] = r14_hs[tb*128 + c];
    __syncthreads();
    if (c < 150) {
        float s = babc[c];
        for (int j = 0; j < 128; j++) s += h_lds[j]*wabc[j*150 + c];
        if (c < 100) { r14_A[tb*100 + c] = s; dout[OUT_A + tb*100 + c] = s; }
        else         { r14_C[tb*50 + (c-100)] = s; dout[OUT_C + tb*50 + (c-100)] = s; }
    }
}

// ============================ Kalman filter (r15: 6-phase, in-register solve, prefetch) ============================
__global__ __launch_bounds__(128) void kf_r15(float* __restrict__ dout)
{
    const int b = blockIdx.x, tid = threadIdx.x;
    const int i10 = tid/10, j10 = tid%10;
    __shared__ float Ab[2][100], Cb[2][56], avb[2][8];
    __shared__ float z[12], P[100], zh[12], AP[100], Ph[100], resid[8],
                     CPm[52], PCt[52], Ssh[28], Kg[52];

    // prologue: init state, stage t=0, issue prefetch of t=1
    float rA = 0.f, rC = 0.f, rav = 0.f;
    if (tid < 100) rA  = r14_A[(0*3+b)*100 + tid];
    if (tid < 50)  rC  = r14_C[(0*3+b)*50 + tid];
    if (tid < 5)   rav = r14_aall[(b*128+0)*5 + tid];
    if (tid < 100) P[tid] = (i10==j10) ? 1.f : 0.f;
    if (tid < 10)  z[tid] = 0.f;
    if (tid < 100) Ab[0][tid] = rA;
    if (tid < 50)  Cb[0][tid] = rC;
    if (tid < 5)   avb[0][tid] = rav;
    if (tid < 100) rA  = r14_A[(1*3+b)*100 + tid];
    if (tid < 50)  rC  = r14_C[(1*3+b)*50 + tid];
    if (tid < 5)   rav = r14_aall[(b*128+1)*5 + tid];
    __syncthreads();

    for (int t = 0; t < 128; t++) {
        const int cb = t & 1, nb = cb ^ 1;
        const float* Ax = Ab[cb];
        const float* Cx = Cb[cb];

        // P1: AP = A@P (lanes 0-99) || zh = A@z (lanes 100-109)
        if (tid < 100) {
            float s = 0.f;
            #pragma unroll
            for (int k = 0; k < 10; k++) s += Ax[i10*10+k]*P[k*10+j10];
            AP[tid] = s;
        } else if (tid < 110) {
            const int i = tid - 100;
            float s = 0.f;
            #pragma unroll
            for (int k = 0; k < 10; k++) s += Ax[i*10+k]*z[k];
            zh[i] = s;
        }
        __syncthreads();

        // P2: Ph = AP@A^T + Q (lanes 0-99) || resid = a - C@zh (lanes 100-104)
        if (tid < 100) {
            float s = (i10==j10) ? 0.08f : 0.f;
            #pragma unroll
            for (int k = 0; k < 10; k++) s += AP[i10*10+k]*Ax[j10*10+k];
            Ph[tid] = s;
        } else if (tid < 105) {
            const int c = tid - 100;
            float s = avb[cb][c];
            #pragma unroll
            for (int k = 0; k < 10; k++) s -= Cx[c*10+k]*zh[k];
            resid[c] = s;
        }
        __syncthreads();

        // P3: CPm = C@Ph (lanes 0-49) || PCt = Ph@C^T (lanes 64-113)
        if (tid < 50) {
            const int i = tid/10, j = tid%10;
            float s = 0.f;
            #pragma unroll
            for (int k = 0; k < 10; k++) s += Cx[i*10+k]*Ph[k*10+j];
            CPm[tid] = s;
        } else if (tid >= 64 && tid < 114) {
            const int q = tid-64, i = q/5, j = q%5;
            float s = 0.f;
            #pragma unroll
            for (int k = 0; k < 10; k++) s += Ph[i*10+k]*Cx[j*10+k];
            PCt[q] = s;
        }
        __syncthreads();

        // P4: S = CPm@C^T + R (lanes 0-24)
        if (tid < 25) {
            const int i = tid/5, j = tid%5;
            float s = (i==j) ? 0.03f : 0.f;
            #pragma unroll
            for (int k = 0; k < 10; k++) s += CPm[i*10+k]*Cx[j*10+k];
            Ssh[tid] = s;
        }
        __syncthreads();

        // P5: lanes 0-9 each solve S^T y = PCt[i,:]^T entirely in registers -> K row i
        if (tid < 10) {
            float M[5][5], bb[5], pv[5], x[5];
            #pragma unroll
            for (int r = 0; r < 5; r++)
                #pragma unroll
                for (int c = 0; c < 5; c++) M[r][c] = Ssh[c*5+r];   // M = S^T
            #pragma unroll
            for (int k = 0; k < 5; k++) bb[k] = PCt[tid*5+k];
            #pragma unroll
            for (int k = 0; k < 5; k++) {
                const float p = 1.f/safed(M[k][k]);
                pv[k] = p;
                #pragma unroll
                for (int r = k+1; r < 5; r++) {
                    const float f = M[r][k]*p;
                    #pragma unroll
                    for (int c = k+1; c < 5; c++) M[r][c] -= f*M[k][c];
                    bb[r] -= f*bb[k];
                }
            }
            #pragma unroll
            for (int k = 4; k >= 0; k--) {
                float s = bb[k];
                #pragma unroll
                for (int c = k+1; c < 5; c++) s -= M[k][c]*x[c];
                x[k] = s*pv[k];
            }
            #pragma unroll
            for (int k = 0; k < 5; k++) Kg[tid*5+k] = x[k];
        }
        __syncthreads();

        // P6: Pn = Ph - K@CPm -> P, pz = zh + K@resid -> z, all stores, next-tile staging
        if (tid < 100) {
            float s = Ph[tid];
            #pragma unroll
            for (int k = 0; k < 5; k++) s -= Kg[i10*5+k]*CPm[k*10+j10];
            r14_pp[(t*3+b)*100 + tid] = s;
            P[tid] = s;
            r14_phat[(t*3+b)*100 + tid] = fmaxf(Ph[tid], (i10==j10)?1e-4f:0.f);
            if (tid < 10) r14_zhat[(t*3+b)*10 + tid] = zh[tid];
        } else if (tid < 110) {
            const int i = tid - 100;
            float s = zh[i];
            #pragma unroll
            for (int k = 0; k < 5; k++) s += Kg[i*5+k]*resid[k];
            r14_pz[(t*3+b)*10 + i] = s;
            z[i] = s;
        }
        if (t < 127) {
            if (tid < 100) Ab[nb][tid] = rA;
            if (tid < 50)  Cb[nb][tid] = rC;
            if (tid < 5)   avb[nb][tid] = rav;
            if (t < 126) {
                if (tid < 100) rA  = r14_A[((t+2)*3+b)*100 + tid];
                if (tid < 50)  rC  = r14_C[((t+2)*3+b)*50 + tid];
                if (tid < 5)   rav = r14_aall[(b*128+(t+2))*5 + tid];
            }
        }
        __syncthreads();
    }
    if (tid < 10)  dout[OUT_LASTZ + b*10 + tid]  = z[tid];
    if (tid < 100) dout[OUT_LASTP + b*100 + tid] = P[tid];
}

// ============================ G = A^T @ inv(Phat_clamped) ============================
__global__ __launch_bounds__(256) void ginv_r14()
{
    const int idx = blockIdx.x;
    const int tt = idx/3 + 1, b = idx%3;
    const int tid = threadIdx.x;
    __shared__ float M[10][21];
    __shared__ float A[100];
    __shared__ int piv;
    if (tid < 100) {
        int i = tid/10, j = tid%10;
        M[i][j] = r14_phat[(tt*3+b)*100 + tid];
        M[i][10+j] = (i==j) ? 1.f : 0.f;
        A[tid] = r14_A[(tt*3+b)*100 + tid];
    }
    __syncthreads();
    const int r = tid/20, cc = tid%20;
    for (int k = 0; k < 10; k++) {
        if (tid == 0) {
            int p = k; float best = fabsf(M[k][k]);
            for (int rr = k+1; rr < 10; rr++) {
                float v = fabsf(M[rr][k]);
                if (v > best) { best = v; p = rr; }
            }
            piv = p;
        }
        __syncthreads();
        if (piv != k && tid < 20) {
            float a = M[k][tid], bb = M[piv][tid];
            M[k][tid] = bb; M[piv][tid] = a;
        }
        __syncthreads();
        float pinv = 1.f/safed(M[k][k]);
        float myf = 0.f, rowv = 0.f;
        if (tid < 200) { myf = M[r][k]; rowv = M[k][cc]; }
        __syncthreads();
        if (tid < 200) {
            if (r == k) M[k][cc] = rowv*pinv;
            else        M[r][cc] -= myf*pinv*rowv;
        }
        __syncthreads();
    }
    if (tid < 100) {
        int i = tid/10, j = tid%10;
        float s = 0.f;
        #pragma unroll
        for (int k = 0; k < 10; k++) s += A[k*10+i]*M[k][10+j];
        r14_G[(tt*3+b)*100 + tid] = s;
    }
}

// ============================ RTS smoother ============================
__global__ __launch_bounds__(128) void rts_r14(float* __restrict__ dout)
{
    const int b = blockIdx.x, tid = threadIdx.x;
    const int i10 = tid/10, j10 = tid%10;
    __shared__ float zc[10], Pc[100], D[100], Gt[100], pPm[100], ph[100],
                     zh[10], pzv[10], dz[10], T1[100], zn[10], Pnn[100];
    if (tid < 10)  zc[tid] = r14_pz[(127*3+b)*10 + tid];
    if (tid < 100) Pc[tid] = r14_pp[(127*3+b)*100 + tid];
    for (int t = 126; t >= 0; t--) {
        __syncthreads();
        if (tid < 100) {
            Gt[tid]  = r14_G[((t+1)*3+b)*100 + tid];
            pPm[tid] = r14_pp[(t*3+b)*100 + tid];
            ph[tid]  = r14_phat[((t+1)*3+b)*100 + tid];
        }
        if (tid < 10) {
            zh[tid]  = r14_zhat[((t+1)*3+b)*10 + tid];
            pzv[tid] = r14_pz[(t*3+b)*10 + tid];
        }
        __syncthreads();
        if (tid < 100){ float s=0.f; for (int k=0;k<10;k++) s += pPm[i10*10+k]*Gt[k*10+j10]; D[tid]=s; }
        if (tid < 10) dz[tid] = zc[tid] - zh[tid];
        __syncthreads();
        if (tid < 10) { float s=pzv[tid]; for (int k=0;k<10;k++) s += D[tid*10+k]*dz[k]; zn[tid]=s; }
        if (tid < 100){ float s=0.f; for (int k=0;k<10;k++) s += D[i10*10+k]*(Pc[k*10+j10]-ph[k*10+j10]); T1[tid]=s; }
        __syncthreads();
        if (tid < 100){ float s=pPm[tid]; for (int k=0;k<10;k++) s += T1[i10*10+k]*D[j10*10+k]; Pnn[tid]=s; }
        __syncthreads();
        if (tid < 10) { dout[OUT_ZS + (b*127+t)*10 + tid] = zn[tid]; zc[tid]=zn[tid]; }
        if (tid < 100){ dout[OUT_PS + (b*127+t)*100 + tid] = Pnn[tid]; Pc[tid]=Pnn[tid]; }
    }
}

// ============================ launch ============================
extern "C" void kernel_launch(void* const* d_in, const int* in_sizes, int n_in,
                              void* d_out, int out_size, void* d_ws, size_t ws_size,
                              hipStream_t stream)
{
    (void)in_sizes; (void)n_in; (void)out_size; (void)d_ws; (void)ws_size;
    const float* images = (const float*)d_in[0];
    const float* w1   = (const float*)d_in[1];
    const float* b1   = (const float*)d_in[2];
    const float* w2   = (const float*)d_in[3];
    const float* b2   = (const float*)d_in[4];
    const float* w3   = (const float*)d_in[5];
    const float* b3   = (const float*)d_in[6];
    const float* wd   = (const float*)d_in[7];
    const float* bd   = (const float*)d_in[8];
    const float* lk   = (const float*)d_in[9];
    const float* lrk  = (const float*)d_in[10];
    const float* lb   = (const float*)d_in[11];
    const float* wabc = (const float*)d_in[12];
    const float* babc = (const float*)d_in[13];
    float* dout = (float*)d_out;   // d_out is FLOAT32 (verified R10)

    u16 *c1p, *c2p, *w2hp, *w2lp, *w3hp, *w3lp;
    hipGetSymbolAddress((void**)&c1p,  HIP_SYMBOL(r14_c1));
    hipGetSymbolAddress((void**)&c2p,  HIP_SYMBOL(r14_c2));
    hipGetSymbolAddress((void**)&w2hp, HIP_SYMBOL(r14_w2h));
    hipGetSymbolAddress((void**)&w2lp, HIP_SYMBOL(r14_w2l));
    hipGetSymbolAddress((void**)&w3hp, HIP_SYMBOL(r14_w3h));
    hipGetSymbolAddress((void**)&w3lp, HIP_SYMBOL(r14_w3l));

    conv1_r14<<<dim3(384), dim3(256), 0, stream>>>(images, w1, b1, c1p);
    w2t_r14<<<dim3(512), dim3(256), 0, stream>>>(w2, w2hp, w2lp);
    w3t_r14<<<dim3(4096), dim3(256), 0, stream>>>(w3, w3hp, w3lp);
    conv2_r14<<<dim3(384, 2), dim3(256), 0, stream>>>(c1p, w2hp, w2lp, b2, c2p);
    conv3_r20<<<dim3(384, 2), dim3(256), 0, stream>>>(c2p, w3hp, w3lp, b3, wd);
    lstm_r20<<<dim3(3), dim3(512), 0, stream>>>(lk, lrk, lb, bd, dout);
    abc_r14<<<dim3(384), dim3(192), 0, stream>>>(wabc, babc, dout);
    kf_r15<<<dim3(3), dim3(128), 0, stream>>>(dout);
    ginv_r14<<<dim3(381), dim3(256), 0, stream>>>();
    rts_r14<<<dim3(3), dim3(128), 0, stream>>>(dout);
}

// Round 8
// 1032.439 us; speedup vs baseline: 1.0732x; 1.0037x over previous
//
#include <hip/hip_runtime.h>
#include <math.h>

typedef unsigned int   u32;
typedef unsigned short u16;
typedef short bf16x8 __attribute__((ext_vector_type(8)));
typedef float f32x4  __attribute__((ext_vector_type(4)));

// ---- output element offsets (d_out is FLOAT32, 101760 elements) ----
#define OUT_ZS    0
#define OUT_PS    3810
#define OUT_AALL  41910
#define OUT_A     43830
#define OUT_C     82230
#define OUT_LASTZ 101430
#define OUT_LASTP 101460

__device__ __forceinline__ float sigm(float x){ return 1.f/(1.f+expf(-x)); }
__device__ __forceinline__ float safed(float d){
    return (fabsf(d) < 1e-30f) ? ((d < 0.f) ? -1e-30f : 1e-30f) : d;
}
__device__ __forceinline__ u16 f2b(float f) {
    union { float f; u32 u; } v; v.f = f;
    u32 r = v.u + 0x7fffu + ((v.u >> 16) & 1u);   // RNE
    return (u16)(r >> 16);
}
__device__ __forceinline__ float b2f(u16 u) {
    union { u32 x; float f; } v; v.x = ((u32)u) << 16; return v.f;
}
__device__ __forceinline__ u32 packb(float a, float b){ return (u32)f2b(a) | ((u32)f2b(b) << 16); }

// ---- static device workspace ----
__device__ u16   r14_c1[25165824];   // conv1 out bf16 NHWC [384][32][32][64]
__device__ u16   r14_c2[12582912];   // conv2 out bf16 NHWC [384][16][16][128]
__device__ u16   r14_w2h[131072];    // w2T hi bf16 [128 oc][1024 k]
__device__ u16   r14_w2l[131072];    // w2T lo bf16
__device__ u16   r14_w3h[1048576];   // w3T hi bf16 [512 oc][2048 k]
__device__ u16   r14_w3l[1048576];   // w3T lo bf16
__device__ float r14_wdT[163840];    // [5][32768] compacted dense weights (5 used cols of 20)
__device__ float r20_dpart[3840];    // dense partials [384 f][2 ocg][5 d]
__device__ float r14_hs[49152];
__device__ float r14_zhat[3840];
__device__ float r14_phat[38400];
__device__ float r14_pz[3840];
__device__ float r14_pp[38400];
__device__ float r14_aall[1920];
__device__ float r14_A[38400];
__device__ float r14_C[19200];
__device__ float r14_G[38400];

// ============================ conv1 (fp32 VALU, bf16 NHWC out) ============================
__global__ __launch_bounds__(256) void conv1_r14(const float* __restrict__ img,
        const float* __restrict__ w1, const float* __restrict__ b1, u16* __restrict__ out)
{
    __shared__ float in_lds[66*66];
    const int f = blockIdx.x, tid = threadIdx.x;
    const int og = tid >> 5, sg = tid & 31;

    for (int i = tid; i < 66*66; i += 256) in_lds[i] = 0.f;
    __syncthreads();
    const float4* src = (const float4*)(img + f*4096);
    for (int i = tid; i < 1024; i += 256) {
        int r = i >> 4, c0 = (i & 15) * 4;
        float4 v = src[i];
        float* dst = &in_lds[(r+1)*66 + c0 + 1];
        dst[0]=v.x; dst[1]=v.y; dst[2]=v.z; dst[3]=v.w;
    }
    float wr[16][8];
    #pragma unroll
    for (int k = 0; k < 16; k++) {
        float4 a = *(const float4*)&w1[k*64 + og*8];
        float4 b = *(const float4*)&w1[k*64 + og*8 + 4];
        wr[k][0]=a.x; wr[k][1]=a.y; wr[k][2]=a.z; wr[k][3]=a.w;
        wr[k][4]=b.x; wr[k][5]=b.y; wr[k][6]=b.z; wr[k][7]=b.w;
    }
    float bias[8];
    #pragma unroll
    for (int j = 0; j < 8; j++) bias[j] = b1[og*8+j];
    __syncthreads();

    for (int yy = 0; yy < 32; yy++) {
        float inv[16];
        #pragma unroll
        for (int ky = 0; ky < 4; ky++)
            #pragma unroll
            for (int kx = 0; kx < 4; kx++)
                inv[ky*4+kx] = in_lds[(2*yy+ky)*66 + 2*sg+kx];
        float acc[8];
        #pragma unroll
        for (int j = 0; j < 8; j++) acc[j] = bias[j];
        #pragma unroll
        for (int k = 0; k < 16; k++)
            #pragma unroll
            for (int j = 0; j < 8; j++) acc[j] += inv[k]*wr[k][j];
        #pragma unroll
        for (int j = 0; j < 8; j++) acc[j] = fmaxf(acc[j], 0.f);
        uint4 pk = make_uint4(packb(acc[0],acc[1]), packb(acc[2],acc[3]),
                              packb(acc[4],acc[5]), packb(acc[6],acc[7]));
        *(uint4*)(out + (f*1024 + yy*32 + sg)*64 + og*8) = pk;
    }
}

// ============================ weight transpose + bf16 split ============================
__global__ __launch_bounds__(256) void w2t_r14(const float* __restrict__ w2,
        u16* __restrict__ hi, u16* __restrict__ lo)
{
    int idx = blockIdx.x*256 + threadIdx.x;
    if (idx < 131072) {
        int k = idx >> 7, oc = idx & 127;
        float v = w2[idx];
        u16 h = f2b(v);
        hi[oc*1024 + k] = h;
        lo[oc*1024 + k] = f2b(v - b2f(h));
    }
}
__global__ __launch_bounds__(256) void w3t_r14(const float* __restrict__ w3,
        u16* __restrict__ hi, u16* __restrict__ lo)
{
    int idx = blockIdx.x*256 + threadIdx.x;
    if (idx < 1048576) {
        int k = idx >> 9, oc = idx & 511;
        float v = w3[idx];
        u16 h = f2b(v);
        hi[oc*2048 + k] = h;
        lo[oc*2048 + k] = f2b(v - b2f(h));
    }
}
__global__ __launch_bounds__(256) void wdt_r14(const float* __restrict__ wd, float* __restrict__ wdT)
{
    int idx = blockIdx.x*256 + threadIdx.x;
    if (idx < 163840) {
        int j = idx & 32767, d = idx >> 15;
        wdT[d*32768 + j] = wd[j*20 + d];
    }
}

// ============================ conv2 MFMA (r14: per-tap staging) ============================
__global__ __launch_bounds__(256) void conv2_r14(const u16* __restrict__ c1b,
        const u16* __restrict__ w2h, const u16* __restrict__ w2l,
        const float* __restrict__ b2, u16* __restrict__ c2b)
{
    __shared__ __align__(16) u16 slab[128*72];
    const int f = blockIdx.x, mc = blockIdx.y, tid = threadIdx.x;
    const int wave = tid >> 6, lane = tid & 63, quad = lane >> 4, ln = lane & 15;

    f32x4 acc[8][2];
    const f32x4 zz = {0.f, 0.f, 0.f, 0.f};
    #pragma unroll
    for (int mt = 0; mt < 8; mt++) { acc[mt][0] = zz; acc[mt][1] = zz; }

    const int sp = tid >> 1;
    const int sy = mc*8 + (sp >> 4), sx = sp & 15;
    const int sic = (tid & 1) * 32;

    for (int kk = 0; kk < 16; kk++) {
        const int ky = kk >> 2, kx = kk & 3;
        __syncthreads();
        {
            int iy = 2*sy - 1 + ky, ix = 2*sx - 1 + kx;
            uint4* d4 = (uint4*)&slab[sp*72 + sic];
            if (iy >= 0 && iy < 32 && ix >= 0 && ix < 32) {
                const uint4* s4 = (const uint4*)&c1b[((f*32 + iy)*32 + ix)*64 + sic];
                d4[0]=s4[0]; d4[1]=s4[1]; d4[2]=s4[2]; d4[3]=s4[3];
            } else {
                uint4 z = make_uint4(0,0,0,0);
                d4[0]=z; d4[1]=z; d4[2]=z; d4[3]=z;
            }
        }
        __syncthreads();
        #pragma unroll
        for (int ks = 0; ks < 2; ks++) {
            bf16x8 af[8];
            #pragma unroll
            for (int mt = 0; mt < 8; mt++)
                af[mt] = *(const bf16x8*)&slab[(mt*16 + ln)*72 + ks*32 + quad*8];
            #pragma unroll
            for (int nt = 0; nt < 2; nt++) {
                const int oc = wave*32 + nt*16 + ln;
                const int kb = kk*64 + ks*32 + quad*8;
                bf16x8 bh = *(const bf16x8*)&w2h[oc*1024 + kb];
                bf16x8 bl = *(const bf16x8*)&w2l[oc*1024 + kb];
                #pragma unroll
                for (int mt = 0; mt < 8; mt++) {
                    acc[mt][nt] = __builtin_amdgcn_mfma_f32_16x16x32_bf16(af[mt], bh, acc[mt][nt], 0,0,0);
                    acc[mt][nt] = __builtin_amdgcn_mfma_f32_16x16x32_bf16(af[mt], bl, acc[mt][nt], 0,0,0);
                }
            }
        }
    }
    #pragma unroll
    for (int nt = 0; nt < 2; nt++) {
        const int oc = wave*32 + nt*16 + ln;
        const float bias = b2[oc];
        #pragma unroll
        for (int mt = 0; mt < 8; mt++)
            #pragma unroll
            for (int r = 0; r < 4; r++) {
                int pix = mc*128 + mt*16 + quad*4 + r;
                c2b[(f*256 + pix)*128 + oc] = f2b(fmaxf(acc[mt][nt][r] + bias, 0.f));
            }
    }
}

// ============================ conv3 MFMA (r20b: fused dense partials via compacted wdT) ============================
__global__ __launch_bounds__(256) void conv3_r20b(const u16* __restrict__ c2b,
        const u16* __restrict__ w3h, const u16* __restrict__ w3l,
        const float* __restrict__ b3)
{
    __shared__ __align__(16) u16 slab[64*136];
    const int f = blockIdx.x, ocg = blockIdx.y, tid = threadIdx.x;
    const int wave = tid >> 6, lane = tid & 63, quad = lane >> 4, ln = lane & 15;
    const int wn = ocg*256 + wave*64;

    f32x4 acc[4][4];
    const f32x4 zz = {0.f, 0.f, 0.f, 0.f};
    #pragma unroll
    for (int mt = 0; mt < 4; mt++)
        #pragma unroll
        for (int nt = 0; nt < 4; nt++) acc[mt][nt] = zz;

    const int sp = tid >> 2;
    const int sy = sp >> 3, sx = sp & 7;
    const int sic = (tid & 3) * 32;

    for (int kk = 0; kk < 16; kk++) {
        const int ky = kk >> 2, kx = kk & 3;
        __syncthreads();
        {
            int iy = 2*sy - 1 + ky, ix = 2*sx - 1 + kx;
            uint4* d4 = (uint4*)&slab[sp*136 + sic];
            if (iy >= 0 && iy < 16 && ix >= 0 && ix < 16) {
                const uint4* s4 = (const uint4*)&c2b[((f*16 + iy)*16 + ix)*128 + sic];
                d4[0]=s4[0]; d4[1]=s4[1]; d4[2]=s4[2]; d4[3]=s4[3];
            } else {
                uint4 z = make_uint4(0,0,0,0);
                d4[0]=z; d4[1]=z; d4[2]=z; d4[3]=z;
            }
        }
        __syncthreads();
        #pragma unroll
        for (int ks = 0; ks < 4; ks++) {
            bf16x8 af[4];
            #pragma unroll
            for (int mt = 0; mt < 4; mt++)
                af[mt] = *(const bf16x8*)&slab[(mt*16 + ln)*136 + ks*32 + quad*8];
            #pragma unroll
            for (int nt = 0; nt < 4; nt++) {
                const int oc = wn + nt*16 + ln;
                const int kb = kk*128 + ks*32 + quad*8;
                bf16x8 bh = *(const bf16x8*)&w3h[oc*2048 + kb];
                bf16x8 bl = *(const bf16x8*)&w3l[oc*2048 + kb];
                #pragma unroll
                for (int mt = 0; mt < 4; mt++) {
                    acc[mt][nt] = __builtin_amdgcn_mfma_f32_16x16x32_bf16(af[mt], bh, acc[mt][nt], 0,0,0);
                    acc[mt][nt] = __builtin_amdgcn_mfma_f32_16x16x32_bf16(af[mt], bl, acc[mt][nt], 0,0,0);
                }
            }
        }
    }

    // fused dense partial sums via compacted wdT [5][32768]: coalesced across ln (oc-contiguous)
    float pd0=0.f, pd1=0.f, pd2=0.f, pd3=0.f, pd4=0.f;
    #pragma unroll
    for (int nt = 0; nt < 4; nt++) {
        const int oc = wn + nt*16 + ln;
        const float bias = b3[oc];
        #pragma unroll
        for (int mt = 0; mt < 4; mt++)
            #pragma unroll
            for (int r = 0; r < 4; r++) {
                const int pix = mt*16 + quad*4 + r;
                const float v = fmaxf(acc[mt][nt][r] + bias, 0.f);
                const float* wp = &r14_wdT[pix*512 + oc];
                pd0 += v*wp[0];
                pd1 += v*wp[32768];
                pd2 += v*wp[65536];
                pd3 += v*wp[98304];
                pd4 += v*wp[131072];
            }
    }
    __syncthreads();                 // done reading slab as u16
    float* red = (float*)slab;       // [5][256] floats = 5 KB < 17 KB
    red[0*256+tid]=pd0; red[1*256+tid]=pd1; red[2*256+tid]=pd2;
    red[3*256+tid]=pd3; red[4*256+tid]=pd4;
    __syncthreads();
    for (int st = 128; st > 0; st >>= 1) {
        if (tid < st) {
            #pragma unroll
            for (int d = 0; d < 5; d++) red[d*256+tid] += red[d*256+tid+st];
        }
        __syncthreads();
    }
    if (tid < 5) r20_dpart[(f*2 + ocg)*5 + tid] = red[tid*256];
}

// ============================ LSTM (r20: finalizes a_all from dense partials) ============================
__global__ __launch_bounds__(512) void lstm_r20(const float* __restrict__ lk,
        const float* __restrict__ lrk, const float* __restrict__ lb,
        const float* __restrict__ bd, float* __restrict__ dout)
{
    const int b = blockIdx.x, c = threadIdx.x;   // c = gate column 0..511
    __shared__ float a_lds[640];
    __shared__ float h_lds[128];
    __shared__ float g_lds[512];
    for (int i = c; i < 640; i += 512) {
        const int f = b*128 + i/5, d = i % 5;
        const float v = bd[d] + r20_dpart[f*10 + d] + r20_dpart[f*10 + 5 + d];
        a_lds[i] = v;
        r14_aall[f*5 + d] = v;
        dout[OUT_AALL + f*5 + d] = v;
    }
    if (c < 128) h_lds[c] = 0.f;
    float wreg[128];                    // lrk column resident in VGPRs
    #pragma unroll
    for (int j = 0; j < 128; j++) wreg[j] = lrk[j*512 + c];
    float lkr[5];
    #pragma unroll
    for (int d = 0; d < 5; d++) lkr[d] = lk[d*512 + c];
    const float gb = lb[c];
    float cs = 0.f;
    __syncthreads();
    for (int t = 0; t < 128; t++) {
        float g = gb;
        if (t > 0) {
            #pragma unroll
            for (int d = 0; d < 5; d++) g += a_lds[(t-1)*5 + d] * lkr[d];
        }
        float s0=0.f, s1=0.f, s2=0.f, s3=0.f;   // 4 chains to break fp-add dependence
        #pragma unroll
        for (int j = 0; j < 128; j += 4) {
            float4 h4 = *(const float4*)&h_lds[j];
            s0 += h4.x*wreg[j];   s1 += h4.y*wreg[j+1];
            s2 += h4.z*wreg[j+2]; s3 += h4.w*wreg[j+3];
        }
        g += (s0 + s1) + (s2 + s3);
        g_lds[c] = g;
        __syncthreads();
        if (c < 128) {
            float gi = g_lds[c], gf = g_lds[c+128], gg = g_lds[c+256], go = g_lds[c+384];
            cs = sigm(gf)*cs + sigm(gi)*tanhf(gg);
            float hn = sigm(go)*tanhf(cs);
            h_lds[c] = hn;
            r14_hs[(t*3 + b)*128 + c] = hn;
        }
        __syncthreads();
    }
}

// ============================ abc -> A, C ============================
__global__ __launch_bounds__(192) void abc_r14(const float* __restrict__ wabc,
        const float* __restrict__ babc, float* __restrict__ dout)
{
    const int tb = blockIdx.x, c = threadIdx.x;
    __shared__ float h_lds[128];
    if (c < 128) h_lds[c] = r14_hs[tb*128 + c];
    __syncthreads();
    if (c < 150) {
        float s = babc[c];
        for (int j = 0; j < 128; j++) s += h_lds[j]*wabc[j*150 + c];
        if (c < 100) { r14_A[tb*100 + c] = s; dout[OUT_A + tb*100 + c] = s; }
        else         { r14_C[tb*50 + (c-100)] = s; dout[OUT_C + tb*50 + (c-100)] = s; }
    }
}

// ============================ Kalman filter (r15: 6-phase, in-register solve, prefetch) ============================
__global__ __launch_bounds__(128) void kf_r15(float* __restrict__ dout)
{
    const int b = blockIdx.x, tid = threadIdx.x;
    const int i10 = tid/10, j10 = tid%10;
    __shared__ float Ab[2][100], Cb[2][56], avb[2][8];
    __shared__ float z[12], P[100], zh[12], AP[100], Ph[100], resid[8],
                     CPm[52], PCt[52], Ssh[28], Kg[52];

    // prologue: init state, stage t=0, issue prefetch of t=1
    float rA = 0.f, rC = 0.f, rav = 0.f;
    if (tid < 100) rA  = r14_A[(0*3+b)*100 + tid];
    if (tid < 50)  rC  = r14_C[(0*3+b)*50 + tid];
    if (tid < 5)   rav = r14_aall[(b*128+0)*5 + tid];
    if (tid < 100) P[tid] = (i10==j10) ? 1.f : 0.f;
    if (tid < 10)  z[tid] = 0.f;
    if (tid < 100) Ab[0][tid] = rA;
    if (tid < 50)  Cb[0][tid] = rC;
    if (tid < 5)   avb[0][tid] = rav;
    if (tid < 100) rA  = r14_A[(1*3+b)*100 + tid];
    if (tid < 50)  rC  = r14_C[(1*3+b)*50 + tid];
    if (tid < 5)   rav = r14_aall[(b*128+1)*5 + tid];
    __syncthreads();

    for (int t = 0; t < 128; t++) {
        const int cb = t & 1, nb = cb ^ 1;
        const float* Ax = Ab[cb];
        const float* Cx = Cb[cb];

        // P1: AP = A@P (lanes 0-99) || zh = A@z (lanes 100-109)
        if (tid < 100) {
            float s = 0.f;
            #pragma unroll
            for (int k = 0; k < 10; k++) s += Ax[i10*10+k]*P[k*10+j10];
            AP[tid] = s;
        } else if (tid < 110) {
            const int i = tid - 100;
            float s = 0.f;
            #pragma unroll
            for (int k = 0; k < 10; k++) s += Ax[i*10+k]*z[k];
            zh[i] = s;
        }
        __syncthreads();

        // P2: Ph = AP@A^T + Q (lanes 0-99) || resid = a - C@zh (lanes 100-104)
        if (tid < 100) {
            float s = (i10==j10) ? 0.08f : 0.f;
            #pragma unroll
            for (int k = 0; k < 10; k++) s += AP[i10*10+k]*Ax[j10*10+k];
            Ph[tid] = s;
        } else if (tid < 105) {
            const int c = tid - 100;
            float s = avb[cb][c];
            #pragma unroll
            for (int k = 0; k < 10; k++) s -= Cx[c*10+k]*zh[k];
            resid[c] = s;
        }
        __syncthreads();

        // P3: CPm = C@Ph (lanes 0-49) || PCt = Ph@C^T (lanes 64-113)
        if (tid < 50) {
            const int i = tid/10, j = tid%10;
            float s = 0.f;
            #pragma unroll
            for (int k = 0; k < 10; k++) s += Cx[i*10+k]*Ph[k*10+j];
            CPm[tid] = s;
        } else if (tid >= 64 && tid < 114) {
            const int q = tid-64, i = q/5, j = q%5;
            float s = 0.f;
            #pragma unroll
            for (int k = 0; k < 10; k++) s += Ph[i*10+k]*Cx[j*10+k];
            PCt[q] = s;
        }
        __syncthreads();

        // P4: S = CPm@C^T + R (lanes 0-24)
        if (tid < 25) {
            const int i = tid/5, j = tid%5;
            float s = (i==j) ? 0.03f : 0.f;
            #pragma unroll
            for (int k = 0; k < 10; k++) s += CPm[i*10+k]*Cx[j*10+k];
            Ssh[tid] = s;
        }
        __syncthreads();

        // P5: lanes 0-9 each solve S^T y = PCt[i,:]^T entirely in registers -> K row i
        if (tid < 10) {
            float M[5][5], bb[5], pv[5], x[5];
            #pragma unroll
            for (int r = 0; r < 5; r++)
                #pragma unroll
                for (int c = 0; c < 5; c++) M[r][c] = Ssh[c*5+r];   // M = S^T
            #pragma unroll
            for (int k = 0; k < 5; k++) bb[k] = PCt[tid*5+k];
            #pragma unroll
            for (int k = 0; k < 5; k++) {
                const float p = 1.f/safed(M[k][k]);
                pv[k] = p;
                #pragma unroll
                for (int r = k+1; r < 5; r++) {
                    const float f = M[r][k]*p;
                    #pragma unroll
                    for (int c = k+1; c < 5; c++) M[r][c] -= f*M[k][c];
                    bb[r] -= f*bb[k];
                }
            }
            #pragma unroll
            for (int k = 4; k >= 0; k--) {
                float s = bb[k];
                #pragma unroll
                for (int c = k+1; c < 5; c++) s -= M[k][c]*x[c];
                x[k] = s*pv[k];
            }
            #pragma unroll
            for (int k = 0; k < 5; k++) Kg[tid*5+k] = x[k];
        }
        __syncthreads();

        // P6: Pn = Ph - K@CPm -> P, pz = zh + K@resid -> z, all stores, next-tile staging
        if (tid < 100) {
            float s = Ph[tid];
            #pragma unroll
            for (int k = 0; k < 5; k++) s -= Kg[i10*5+k]*CPm[k*10+j10];
            r14_pp[(t*3+b)*100 + tid] = s;
            P[tid] = s;
            r14_phat[(t*3+b)*100 + tid] = fmaxf(Ph[tid], (i10==j10)?1e-4f:0.f);
            if (tid < 10) r14_zhat[(t*3+b)*10 + tid] = zh[tid];
        } else if (tid < 110) {
            const int i = tid - 100;
            float s = zh[i];
            #pragma unroll
            for (int k = 0; k < 5; k++) s += Kg[i*5+k]*resid[k];
            r14_pz[(t*3+b)*10 + i] = s;
            z[i] = s;
        }
        if (t < 127) {
            if (tid < 100) Ab[nb][tid] = rA;
            if (tid < 50)  Cb[nb][tid] = rC;
            if (tid < 5)   avb[nb][tid] = rav;
            if (t < 126) {
                if (tid < 100) rA  = r14_A[((t+2)*3+b)*100 + tid];
                if (tid < 50)  rC  = r14_C[((t+2)*3+b)*50 + tid];
                if (tid < 5)   rav = r14_aall[(b*128+(t+2))*5 + tid];
            }
        }
        __syncthreads();
    }
    if (tid < 10)  dout[OUT_LASTZ + b*10 + tid]  = z[tid];
    if (tid < 100) dout[OUT_LASTP + b*100 + tid] = P[tid];
}

// ============================ G = A^T @ inv(Phat_clamped) ============================
__global__ __launch_bounds__(256) void ginv_r14()
{
    const int idx = blockIdx.x;
    const int tt = idx/3 + 1, b = idx%3;
    const int tid = threadIdx.x;
    __shared__ float M[10][21];
    __shared__ float A[100];
    __shared__ int piv;
    if (tid < 100) {
        int i = tid/10, j = tid%10;
        M[i][j] = r14_phat[(tt*3+b)*100 + tid];
        M[i][10+j] = (i==j) ? 1.f : 0.f;
        A[tid] = r14_A[(tt*3+b)*100 + tid];
    }
    __syncthreads();
    const int r = tid/20, cc = tid%20;
    for (int k = 0; k < 10; k++) {
        if (tid == 0) {
            int p = k; float best = fabsf(M[k][k]);
            for (int rr = k+1; rr < 10; rr++) {
                float v = fabsf(M[rr][k]);
                if (v > best) { best = v; p = rr; }
            }
            piv = p;
        }
        __syncthreads();
        if (piv != k && tid < 20) {
            float a = M[k][tid], bb = M[piv][tid];
            M[k][tid] = bb; M[piv][tid] = a;
        }
        __syncthreads();
        float pinv = 1.f/safed(M[k][k]);
        float myf = 0.f, rowv = 0.f;
        if (tid < 200) { myf = M[r][k]; rowv = M[k][cc]; }
        __syncthreads();
        if (tid < 200) {
            if (r == k) M[k][cc] = rowv*pinv;
            else        M[r][cc] -= myf*pinv*rowv;
        }
        __syncthreads();
    }
    if (tid < 100) {
        int i = tid/10, j = tid%10;
        float s = 0.f;
        #pragma unroll
        for (int k = 0; k < 10; k++) s += A[k*10+i]*M[k][10+j];
        r14_G[(tt*3+b)*100 + tid] = s;
    }
}

// ============================ RTS smoother ============================
__global__ __launch_bounds__(128) void rts_r14(float* __restrict__ dout)
{
    const int b = blockIdx.x, tid = threadIdx.x;
    const int i10 = tid/10, j10 = tid%10;
    __shared__ float zc[10], Pc[100], D[100], Gt[100], pPm[100], ph[100],
                     zh[10], pzv[10], dz[10], T1[100], zn[10], Pnn[100];
    if (tid < 10)  zc[tid] = r14_pz[(127*3+b)*10 + tid];
    if (tid < 100) Pc[tid] = r14_pp[(127*3+b)*100 + tid];
    for (int t = 126; t >= 0; t--) {
        __syncthreads();
        if (tid < 100) {
            Gt[tid]  = r14_G[((t+1)*3+b)*100 + tid];
            pPm[tid] = r14_pp[(t*3+b)*100 + tid];
            ph[tid]  = r14_phat[((t+1)*3+b)*100 + tid];
        }
        if (tid < 10) {
            zh[tid]  = r14_zhat[((t+1)*3+b)*10 + tid];
            pzv[tid] = r14_pz[(t*3+b)*10 + tid];
        }
        __syncthreads();
        if (tid < 100){ float s=0.f; for (int k=0;k<10;k++) s += pPm[i10*10+k]*Gt[k*10+j10]; D[tid]=s; }
        if (tid < 10) dz[tid] = zc[tid] - zh[tid];
        __syncthreads();
        if (tid < 10) { float s=pzv[tid]; for (int k=0;k<10;k++) s += D[tid*10+k]*dz[k]; zn[tid]=s; }
        if (tid < 100){ float s=0.f; for (int k=0;k<10;k++) s += D[i10*10+k]*(Pc[k*10+j10]-ph[k*10+j10]); T1[tid]=s; }
        __syncthreads();
        if (tid < 100){ float s=pPm[tid]; for (int k=0;k<10;k++) s += T1[i10*10+k]*D[j10*10+k]; Pnn[tid]=s; }
        __syncthreads();
        if (tid < 10) { dout[OUT_ZS + (b*127+t)*10 + tid] = zn[tid]; zc[tid]=zn[tid]; }
        if (tid < 100){ dout[OUT_PS + (b*127+t)*100 + tid] = Pnn[tid]; Pc[tid]=Pnn[tid]; }
    }
}

// ============================ launch ============================
extern "C" void kernel_launch(void* const* d_in, const int* in_sizes, int n_in,
                              void* d_out, int out_size, void* d_ws, size_t ws_size,
                              hipStream_t stream)
{
    (void)in_sizes; (void)n_in; (void)out_size; (void)d_ws; (void)ws_size;
    const float* images = (const float*)d_in[0];
    const float* w1   = (const float*)d_in[1];
    const float* b1   = (const float*)d_in[2];
    const float* w2   = (const float*)d_in[3];
    const float* b2   = (const float*)d_in[4];
    const float* w3   = (const float*)d_in[5];
    const float* b3   = (const float*)d_in[6];
    const float* wd   = (const float*)d_in[7];
    const float* bd   = (const float*)d_in[8];
    const float* lk   = (const float*)d_in[9];
    const float* lrk  = (const float*)d_in[10];
    const float* lb   = (const float*)d_in[11];
    const float* wabc = (const float*)d_in[12];
    const float* babc = (const float*)d_in[13];
    float* dout = (float*)d_out;   // d_out is FLOAT32 (verified R10)

    u16 *c1p, *c2p, *w2hp, *w2lp, *w3hp, *w3lp;
    float *wdTp;
    hipGetSymbolAddress((void**)&c1p,  HIP_SYMBOL(r14_c1));
    hipGetSymbolAddress((void**)&c2p,  HIP_SYMBOL(r14_c2));
    hipGetSymbolAddress((void**)&w2hp, HIP_SYMBOL(r14_w2h));
    hipGetSymbolAddress((void**)&w2lp, HIP_SYMBOL(r14_w2l));
    hipGetSymbolAddress((void**)&w3hp, HIP_SYMBOL(r14_w3h));
    hipGetSymbolAddress((void**)&w3lp, HIP_SYMBOL(r14_w3l));
    hipGetSymbolAddress((void**)&wdTp, HIP_SYMBOL(r14_wdT));

    conv1_r14<<<dim3(384), dim3(256), 0, stream>>>(images, w1, b1, c1p);
    w2t_r14<<<dim3(512), dim3(256), 0, stream>>>(w2, w2hp, w2lp);
    w3t_r14<<<dim3(4096), dim3(256), 0, stream>>>(w3, w3hp, w3lp);
    wdt_r14<<<dim3(640), dim3(256), 0, stream>>>(wd, wdTp);
    conv2_r14<<<dim3(384, 2), dim3(256), 0, stream>>>(c1p, w2hp, w2lp, b2, c2p);
    conv3_r20b<<<dim3(384, 2), dim3(256), 0, stream>>>(c2p, w3hp, w3lp, b3);
    lstm_r20<<<dim3(3), dim3(512), 0, stream>>>(lk, lrk, lb, bd, dout);
    abc_r14<<<dim3(384), dim3(192), 0, stream>>>(wabc, babc, dout);
    kf_r15<<<dim3(3), dim3(128), 0, stream>>>(dout);
    ginv_r14<<<dim3(381), dim3(256), 0, stream>>>();
    rts_r14<<<dim3(3), dim3(128), 0, stream>>>(dout);
}

// Round 9
// 912.313 us; speedup vs baseline: 1.2145x; 1.1317x over previous
//
#include <hip/hip_runtime.h>
#include <math.h>

typedef unsigned int   u32;
typedef unsigned short u16;
typedef short bf16x8 __attribute__((ext_vector_type(8)));
typedef float f32x4  __attribute__((ext_vector_type(4)));

// ---- output element offsets (d_out is FLOAT32, 101760 elements) ----
#define OUT_ZS    0
#define OUT_PS    3810
#define OUT_AALL  41910
#define OUT_A     43830
#define OUT_C     82230
#define OUT_LASTZ 101430
#define OUT_LASTP 101460

__device__ __forceinline__ float sigm(float x){ return 1.f/(1.f+expf(-x)); }
__device__ __forceinline__ float safed(float d){
    return (fabsf(d) < 1e-30f) ? ((d < 0.f) ? -1e-30f : 1e-30f) : d;
}
__device__ __forceinline__ u16 f2b(float f) {
    union { float f; u32 u; } v; v.f = f;
    u32 r = v.u + 0x7fffu + ((v.u >> 16) & 1u);   // RNE
    return (u16)(r >> 16);
}
__device__ __forceinline__ float b2f(u16 u) {
    union { u32 x; float f; } v; v.x = ((u32)u) << 16; return v.f;
}
__device__ __forceinline__ u32 packb(float a, float b){ return (u32)f2b(a) | ((u32)f2b(b) << 16); }

// ---- static device workspace ----
__device__ u16   r14_c1[25165824];   // conv1 out bf16 NHWC [384][32][32][64]
__device__ u16   r14_c2[12582912];   // conv2 out bf16 NHWC [384][16][16][128]
__device__ u16   r14_w2h[131072];    // w2T hi bf16 [128 oc][1024 k]
__device__ u16   r14_w2l[131072];    // w2T lo bf16
__device__ u16   r14_w3h[1048576];   // w3T hi bf16 [512 oc][2048 k]
__device__ u16   r14_w3l[1048576];   // w3T lo bf16
__device__ float r14_wdT[163840];    // [5][32768] compacted dense weights (5 used cols of 20)
__device__ float r20_dpart[7680];    // dense partials [384 f][4 ocg][5 d]
__device__ float r14_hs[49152];
__device__ float r14_zhat[3840];
__device__ float r14_phat[38400];
__device__ float r14_pz[3840];
__device__ float r14_pp[38400];
__device__ float r14_aall[1920];
__device__ float r14_A[38400];
__device__ float r14_C[19200];
__device__ float r14_G[38400];

// ============================ conv1 (fp32 VALU, bf16 NHWC out) ============================
__global__ __launch_bounds__(256) void conv1_r14(const float* __restrict__ img,
        const float* __restrict__ w1, const float* __restrict__ b1, u16* __restrict__ out)
{
    __shared__ float in_lds[66*66];
    const int f = blockIdx.x, tid = threadIdx.x;
    const int og = tid >> 5, sg = tid & 31;

    for (int i = tid; i < 66*66; i += 256) in_lds[i] = 0.f;
    __syncthreads();
    const float4* src = (const float4*)(img + f*4096);
    for (int i = tid; i < 1024; i += 256) {
        int r = i >> 4, c0 = (i & 15) * 4;
        float4 v = src[i];
        float* dst = &in_lds[(r+1)*66 + c0 + 1];
        dst[0]=v.x; dst[1]=v.y; dst[2]=v.z; dst[3]=v.w;
    }
    float wr[16][8];
    #pragma unroll
    for (int k = 0; k < 16; k++) {
        float4 a = *(const float4*)&w1[k*64 + og*8];
        float4 b = *(const float4*)&w1[k*64 + og*8 + 4];
        wr[k][0]=a.x; wr[k][1]=a.y; wr[k][2]=a.z; wr[k][3]=a.w;
        wr[k][4]=b.x; wr[k][5]=b.y; wr[k][6]=b.z; wr[k][7]=b.w;
    }
    float bias[8];
    #pragma unroll
    for (int j = 0; j < 8; j++) bias[j] = b1[og*8+j];
    __syncthreads();

    for (int yy = 0; yy < 32; yy++) {
        float inv[16];
        #pragma unroll
        for (int ky = 0; ky < 4; ky++)
            #pragma unroll
            for (int kx = 0; kx < 4; kx++)
                inv[ky*4+kx] = in_lds[(2*yy+ky)*66 + 2*sg+kx];
        float acc[8];
        #pragma unroll
        for (int j = 0; j < 8; j++) acc[j] = bias[j];
        #pragma unroll
        for (int k = 0; k < 16; k++)
            #pragma unroll
            for (int j = 0; j < 8; j++) acc[j] += inv[k]*wr[k][j];
        #pragma unroll
        for (int j = 0; j < 8; j++) acc[j] = fmaxf(acc[j], 0.f);
        uint4 pk = make_uint4(packb(acc[0],acc[1]), packb(acc[2],acc[3]),
                              packb(acc[4],acc[5]), packb(acc[6],acc[7]));
        *(uint4*)(out + (f*1024 + yy*32 + sg)*64 + og*8) = pk;
    }
}

// ============================ weight transpose + bf16 split ============================
__global__ __launch_bounds__(256) void w2t_r14(const float* __restrict__ w2,
        u16* __restrict__ hi, u16* __restrict__ lo)
{
    int idx = blockIdx.x*256 + threadIdx.x;
    if (idx < 131072) {
        int k = idx >> 7, oc = idx & 127;
        float v = w2[idx];
        u16 h = f2b(v);
        hi[oc*1024 + k] = h;
        lo[oc*1024 + k] = f2b(v - b2f(h));
    }
}
__global__ __launch_bounds__(256) void w3t_r14(const float* __restrict__ w3,
        u16* __restrict__ hi, u16* __restrict__ lo)
{
    int idx = blockIdx.x*256 + threadIdx.x;
    if (idx < 1048576) {
        int k = idx >> 9, oc = idx & 511;
        float v = w3[idx];
        u16 h = f2b(v);
        hi[oc*2048 + k] = h;
        lo[oc*2048 + k] = f2b(v - b2f(h));
    }
}
__global__ __launch_bounds__(256) void wdt_r14(const float* __restrict__ wd, float* __restrict__ wdT)
{
    int idx = blockIdx.x*256 + threadIdx.x;
    if (idx < 163840) {
        int j = idx & 32767, d = idx >> 15;
        wdT[d*32768 + j] = wd[j*20 + d];
    }
}

// ============================ conv2 MFMA (r14: per-tap staging) ============================
__global__ __launch_bounds__(256) void conv2_r14(const u16* __restrict__ c1b,
        const u16* __restrict__ w2h, const u16* __restrict__ w2l,
        const float* __restrict__ b2, u16* __restrict__ c2b)
{
    __shared__ __align__(16) u16 slab[128*72];
    const int f = blockIdx.x, mc = blockIdx.y, tid = threadIdx.x;
    const int wave = tid >> 6, lane = tid & 63, quad = lane >> 4, ln = lane & 15;

    f32x4 acc[8][2];
    const f32x4 zz = {0.f, 0.f, 0.f, 0.f};
    #pragma unroll
    for (int mt = 0; mt < 8; mt++) { acc[mt][0] = zz; acc[mt][1] = zz; }

    const int sp = tid >> 1;
    const int sy = mc*8 + (sp >> 4), sx = sp & 15;
    const int sic = (tid & 1) * 32;

    for (int kk = 0; kk < 16; kk++) {
        const int ky = kk >> 2, kx = kk & 3;
        __syncthreads();
        {
            int iy = 2*sy - 1 + ky, ix = 2*sx - 1 + kx;
            uint4* d4 = (uint4*)&slab[sp*72 + sic];
            if (iy >= 0 && iy < 32 && ix >= 0 && ix < 32) {
                const uint4* s4 = (const uint4*)&c1b[((f*32 + iy)*32 + ix)*64 + sic];
                d4[0]=s4[0]; d4[1]=s4[1]; d4[2]=s4[2]; d4[3]=s4[3];
            } else {
                uint4 z = make_uint4(0,0,0,0);
                d4[0]=z; d4[1]=z; d4[2]=z; d4[3]=z;
            }
        }
        __syncthreads();
        #pragma unroll
        for (int ks = 0; ks < 2; ks++) {
            bf16x8 af[8];
            #pragma unroll
            for (int mt = 0; mt < 8; mt++)
                af[mt] = *(const bf16x8*)&slab[(mt*16 + ln)*72 + ks*32 + quad*8];
            #pragma unroll
            for (int nt = 0; nt < 2; nt++) {
                const int oc = wave*32 + nt*16 + ln;
                const int kb = kk*64 + ks*32 + quad*8;
                bf16x8 bh = *(const bf16x8*)&w2h[oc*1024 + kb];
                bf16x8 bl = *(const bf16x8*)&w2l[oc*1024 + kb];
                #pragma unroll
                for (int mt = 0; mt < 8; mt++) {
                    acc[mt][nt] = __builtin_amdgcn_mfma_f32_16x16x32_bf16(af[mt], bh, acc[mt][nt], 0,0,0);
                    acc[mt][nt] = __builtin_amdgcn_mfma_f32_16x16x32_bf16(af[mt], bl, acc[mt][nt], 0,0,0);
                }
            }
        }
    }
    #pragma unroll
    for (int nt = 0; nt < 2; nt++) {
        const int oc = wave*32 + nt*16 + ln;
        const float bias = b2[oc];
        #pragma unroll
        for (int mt = 0; mt < 8; mt++)
            #pragma unroll
            for (int r = 0; r < 4; r++) {
                int pix = mc*128 + mt*16 + quad*4 + r;
                c2b[(f*256 + pix)*128 + oc] = f2b(fmaxf(acc[mt][nt][r] + bias, 0.f));
            }
    }
}

// ============================ conv3 MFMA (r21: 2-frame weight reuse + fused dense) ============================
// grid (192, 4): blockIdx.x = frame-pair fp, blockIdx.y = ocg (128 oc).
// Each weight fetch (bh/bl) feeds MFMAs for BOTH frames -> weight traffic per frame halved.
__global__ __launch_bounds__(256, 3) void conv3_r21(const u16* __restrict__ c2b,
        const u16* __restrict__ w3h, const u16* __restrict__ w3l,
        const float* __restrict__ b3)
{
    __shared__ __align__(16) u16 slab[2][64*136];
    const int fp = blockIdx.x, ocg = blockIdx.y, tid = threadIdx.x;
    const int wave = tid >> 6, lane = tid & 63, quad = lane >> 4, ln = lane & 15;
    const int wn = ocg*128 + wave*32;

    f32x4 acc[2][4][2];
    const f32x4 zz = {0.f, 0.f, 0.f, 0.f};
    #pragma unroll
    for (int f2 = 0; f2 < 2; f2++)
        #pragma unroll
        for (int mt = 0; mt < 4; mt++) { acc[f2][mt][0] = zz; acc[f2][mt][1] = zz; }

    const int sp = tid >> 2;
    const int sy = sp >> 3, sx = sp & 7;
    const int sic = (tid & 3) * 32;

    for (int kk = 0; kk < 16; kk++) {
        const int ky = kk >> 2, kx = kk & 3;
        const int iy = 2*sy - 1 + ky, ix = 2*sx - 1 + kx;
        const bool vin = (iy >= 0 && iy < 16 && ix >= 0 && ix < 16);
        __syncthreads();
        #pragma unroll
        for (int f2 = 0; f2 < 2; f2++) {
            const int f = fp*2 + f2;
            uint4* d4 = (uint4*)&slab[f2][sp*136 + sic];
            if (vin) {
                const uint4* s4 = (const uint4*)&c2b[((f*16 + iy)*16 + ix)*128 + sic];
                d4[0]=s4[0]; d4[1]=s4[1]; d4[2]=s4[2]; d4[3]=s4[3];
            } else {
                uint4 z = make_uint4(0,0,0,0);
                d4[0]=z; d4[1]=z; d4[2]=z; d4[3]=z;
            }
        }
        __syncthreads();
        #pragma unroll
        for (int ks = 0; ks < 4; ks++) {
            bf16x8 af[2][4];
            #pragma unroll
            for (int f2 = 0; f2 < 2; f2++)
                #pragma unroll
                for (int mt = 0; mt < 4; mt++)
                    af[f2][mt] = *(const bf16x8*)&slab[f2][(mt*16 + ln)*136 + ks*32 + quad*8];
            const int kb = kk*128 + ks*32 + quad*8;
            #pragma unroll
            for (int nt = 0; nt < 2; nt++) {
                const int oc = wn + nt*16 + ln;
                bf16x8 bh = *(const bf16x8*)&w3h[oc*2048 + kb];
                bf16x8 bl = *(const bf16x8*)&w3l[oc*2048 + kb];
                #pragma unroll
                for (int f2 = 0; f2 < 2; f2++)
                    #pragma unroll
                    for (int mt = 0; mt < 4; mt++) {
                        acc[f2][mt][nt] = __builtin_amdgcn_mfma_f32_16x16x32_bf16(af[f2][mt], bh, acc[f2][mt][nt], 0,0,0);
                        acc[f2][mt][nt] = __builtin_amdgcn_mfma_f32_16x16x32_bf16(af[f2][mt], bl, acc[f2][mt][nt], 0,0,0);
                    }
            }
        }
    }

    // fused dense partials (per frame) via compacted wdT
    float pd[2][5];
    #pragma unroll
    for (int f2 = 0; f2 < 2; f2++)
        #pragma unroll
        for (int d = 0; d < 5; d++) pd[f2][d] = 0.f;
    #pragma unroll
    for (int nt = 0; nt < 2; nt++) {
        const int oc = wn + nt*16 + ln;
        const float bias = b3[oc];
        #pragma unroll
        for (int mt = 0; mt < 4; mt++)
            #pragma unroll
            for (int r = 0; r < 4; r++) {
                const int pix = mt*16 + quad*4 + r;
                const float* wp = &r14_wdT[pix*512 + oc];
                const float w0 = wp[0], w1 = wp[32768], w2 = wp[65536],
                            w3v = wp[98304], w4 = wp[131072];
                #pragma unroll
                for (int f2 = 0; f2 < 2; f2++) {
                    const float v = fmaxf(acc[f2][mt][nt][r] + bias, 0.f);
                    pd[f2][0] += v*w0; pd[f2][1] += v*w1; pd[f2][2] += v*w2;
                    pd[f2][3] += v*w3v; pd[f2][4] += v*w4;
                }
            }
    }
    __syncthreads();                 // done reading slab as u16
    float* red = (float*)slab;       // [10][256] floats = 10 KB < 34 KB
    #pragma unroll
    for (int f2 = 0; f2 < 2; f2++)
        #pragma unroll
        for (int d = 0; d < 5; d++) red[(f2*5+d)*256 + tid] = pd[f2][d];
    __syncthreads();
    for (int st = 128; st > 0; st >>= 1) {
        if (tid < st) {
            #pragma unroll
            for (int q = 0; q < 10; q++) red[q*256+tid] += red[q*256+tid+st];
        }
        __syncthreads();
    }
    if (tid < 10) {
        const int f2 = tid/5, d = tid%5;
        r20_dpart[((fp*2+f2)*4 + ocg)*5 + d] = red[tid*256];
    }
}

// ============================ LSTM (r21: finalizes a_all from 4 dense partials) ============================
__global__ __launch_bounds__(512) void lstm_r21(const float* __restrict__ lk,
        const float* __restrict__ lrk, const float* __restrict__ lb,
        const float* __restrict__ bd, float* __restrict__ dout)
{
    const int b = blockIdx.x, c = threadIdx.x;   // c = gate column 0..511
    __shared__ float a_lds[640];
    __shared__ float h_lds[128];
    __shared__ float g_lds[512];
    for (int i = c; i < 640; i += 512) {
        const int f = b*128 + i/5, d = i % 5;
        float v = bd[d];
        #pragma unroll
        for (int g = 0; g < 4; g++) v += r20_dpart[f*20 + g*5 + d];
        a_lds[i] = v;
        r14_aall[f*5 + d] = v;
        dout[OUT_AALL + f*5 + d] = v;
    }
    if (c < 128) h_lds[c] = 0.f;
    float wreg[128];                    // lrk column resident in VGPRs
    #pragma unroll
    for (int j = 0; j < 128; j++) wreg[j] = lrk[j*512 + c];
    float lkr[5];
    #pragma unroll
    for (int d = 0; d < 5; d++) lkr[d] = lk[d*512 + c];
    const float gb = lb[c];
    float cs = 0.f;
    __syncthreads();
    for (int t = 0; t < 128; t++) {
        float g = gb;
        if (t > 0) {
            #pragma unroll
            for (int d = 0; d < 5; d++) g += a_lds[(t-1)*5 + d] * lkr[d];
        }
        float s0=0.f, s1=0.f, s2=0.f, s3=0.f;   // 4 chains to break fp-add dependence
        #pragma unroll
        for (int j = 0; j < 128; j += 4) {
            float4 h4 = *(const float4*)&h_lds[j];
            s0 += h4.x*wreg[j];   s1 += h4.y*wreg[j+1];
            s2 += h4.z*wreg[j+2]; s3 += h4.w*wreg[j+3];
        }
        g += (s0 + s1) + (s2 + s3);
        g_lds[c] = g;
        __syncthreads();
        if (c < 128) {
            float gi = g_lds[c], gf = g_lds[c+128], gg = g_lds[c+256], go = g_lds[c+384];
            cs = sigm(gf)*cs + sigm(gi)*tanhf(gg);
            float hn = sigm(go)*tanhf(cs);
            h_lds[c] = hn;
            r14_hs[(t*3 + b)*128 + c] = hn;
        }
        __syncthreads();
    }
}

// ============================ abc -> A, C ============================
__global__ __launch_bounds__(192) void abc_r14(const float* __restrict__ wabc,
        const float* __restrict__ babc, float* __restrict__ dout)
{
    const int tb = blockIdx.x, c = threadIdx.x;
    __shared__ float h_lds[128];
    if (c < 128) h_lds[c] = r14_hs[tb*128 + c];
    __syncthreads();
    if (c < 150) {
        float s = babc[c];
        for (int j = 0; j < 128; j++) s += h_lds[j]*wabc[j*150 + c];
        if (c < 100) { r14_A[tb*100 + c] = s; dout[OUT_A + tb*100 + c] = s; }
        else         { r14_C[tb*50 + (c-100)] = s; dout[OUT_C + tb*50 + (c-100)] = s; }
    }
}

// ============================ Kalman filter (r15: 6-phase, in-register solve, prefetch) ============================
__global__ __launch_bounds__(128) void kf_r15(float* __restrict__ dout)
{
    const int b = blockIdx.x, tid = threadIdx.x;
    const int i10 = tid/10, j10 = tid%10;
    __shared__ float Ab[2][100], Cb[2][56], avb[2][8];
    __shared__ float z[12], P[100], zh[12], AP[100], Ph[100], resid[8],
                     CPm[52], PCt[52], Ssh[28], Kg[52];

    // prologue: init state, stage t=0, issue prefetch of t=1
    float rA = 0.f, rC = 0.f, rav = 0.f;
    if (tid < 100) rA  = r14_A[(0*3+b)*100 + tid];
    if (tid < 50)  rC  = r14_C[(0*3+b)*50 + tid];
    if (tid < 5)   rav = r14_aall[(b*128+0)*5 + tid];
    if (tid < 100) P[tid] = (i10==j10) ? 1.f : 0.f;
    if (tid < 10)  z[tid] = 0.f;
    if (tid < 100) Ab[0][tid] = rA;
    if (tid < 50)  Cb[0][tid] = rC;
    if (tid < 5)   avb[0][tid] = rav;
    if (tid < 100) rA  = r14_A[(1*3+b)*100 + tid];
    if (tid < 50)  rC  = r14_C[(1*3+b)*50 + tid];
    if (tid < 5)   rav = r14_aall[(b*128+1)*5 + tid];
    __syncthreads();

    for (int t = 0; t < 128; t++) {
        const int cb = t & 1, nb = cb ^ 1;
        const float* Ax = Ab[cb];
        const float* Cx = Cb[cb];

        // P1: AP = A@P (lanes 0-99) || zh = A@z (lanes 100-109)
        if (tid < 100) {
            float s = 0.f;
            #pragma unroll
            for (int k = 0; k < 10; k++) s += Ax[i10*10+k]*P[k*10+j10];
            AP[tid] = s;
        } else if (tid < 110) {
            const int i = tid - 100;
            float s = 0.f;
            #pragma unroll
            for (int k = 0; k < 10; k++) s += Ax[i*10+k]*z[k];
            zh[i] = s;
        }
        __syncthreads();

        // P2: Ph = AP@A^T + Q (lanes 0-99) || resid = a - C@zh (lanes 100-104)
        if (tid < 100) {
            float s = (i10==j10) ? 0.08f : 0.f;
            #pragma unroll
            for (int k = 0; k < 10; k++) s += AP[i10*10+k]*Ax[j10*10+k];
            Ph[tid] = s;
        } else if (tid < 105) {
            const int c = tid - 100;
            float s = avb[cb][c];
            #pragma unroll
            for (int k = 0; k < 10; k++) s -= Cx[c*10+k]*zh[k];
            resid[c] = s;
        }
        __syncthreads();

        // P3: CPm = C@Ph (lanes 0-49) || PCt = Ph@C^T (lanes 64-113)
        if (tid < 50) {
            const int i = tid/10, j = tid%10;
            float s = 0.f;
            #pragma unroll
            for (int k = 0; k < 10; k++) s += Cx[i*10+k]*Ph[k*10+j];
            CPm[tid] = s;
        } else if (tid >= 64 && tid < 114) {
            const int q = tid-64, i = q/5, j = q%5;
            float s = 0.f;
            #pragma unroll
            for (int k = 0; k < 10; k++) s += Ph[i*10+k]*Cx[j*10+k];
            PCt[q] = s;
        }
        __syncthreads();

        // P4: S = CPm@C^T + R (lanes 0-24)
        if (tid < 25) {
            const int i = tid/5, j = tid%5;
            float s = (i==j) ? 0.03f : 0.f;
            #pragma unroll
            for (int k = 0; k < 10; k++) s += CPm[i*10+k]*Cx[j*10+k];
            Ssh[tid] = s;
        }
        __syncthreads();

        // P5: lanes 0-9 each solve S^T y = PCt[i,:]^T entirely in registers -> K row i
        if (tid < 10) {
            float M[5][5], bb[5], pv[5], x[5];
            #pragma unroll
            for (int r = 0; r < 5; r++)
                #pragma unroll
                for (int c = 0; c < 5; c++) M[r][c] = Ssh[c*5+r];   // M = S^T
            #pragma unroll
            for (int k = 0; k < 5; k++) bb[k] = PCt[tid*5+k];
            #pragma unroll
            for (int k = 0; k < 5; k++) {
                const float p = 1.f/safed(M[k][k]);
                pv[k] = p;
                #pragma unroll
                for (int r = k+1; r < 5; r++) {
                    const float f = M[r][k]*p;
                    #pragma unroll
                    for (int c = k+1; c < 5; c++) M[r][c] -= f*M[k][c];
                    bb[r] -= f*bb[k];
                }
            }
            #pragma unroll
            for (int k = 4; k >= 0; k--) {
                float s = bb[k];
                #pragma unroll
                for (int c = k+1; c < 5; c++) s -= M[k][c]*x[c];
                x[k] = s*pv[k];
            }
            #pragma unroll
            for (int k = 0; k < 5; k++) Kg[tid*5+k] = x[k];
        }
        __syncthreads();

        // P6: Pn = Ph - K@CPm -> P, pz = zh + K@resid -> z, all stores, next-tile staging
        if (tid < 100) {
            float s = Ph[tid];
            #pragma unroll
            for (int k = 0; k < 5; k++) s -= Kg[i10*5+k]*CPm[k*10+j10];
            r14_pp[(t*3+b)*100 + tid] = s;
            P[tid] = s;
            r14_phat[(t*3+b)*100 + tid] = fmaxf(Ph[tid], (i10==j10)?1e-4f:0.f);
            if (tid < 10) r14_zhat[(t*3+b)*10 + tid] = zh[tid];
        } else if (tid < 110) {
            const int i = tid - 100;
            float s = zh[i];
            #pragma unroll
            for (int k = 0; k < 5; k++) s += Kg[i*5+k]*resid[k];
            r14_pz[(t*3+b)*10 + i] = s;
            z[i] = s;
        }
        if (t < 127) {
            if (tid < 100) Ab[nb][tid] = rA;
            if (tid < 50)  Cb[nb][tid] = rC;
            if (tid < 5)   avb[nb][tid] = rav;
            if (t < 126) {
                if (tid < 100) rA  = r14_A[((t+2)*3+b)*100 + tid];
                if (tid < 50)  rC  = r14_C[((t+2)*3+b)*50 + tid];
                if (tid < 5)   rav = r14_aall[(b*128+(t+2))*5 + tid];
            }
        }
        __syncthreads();
    }
    if (tid < 10)  dout[OUT_LASTZ + b*10 + tid]  = z[tid];
    if (tid < 100) dout[OUT_LASTP + b*100 + tid] = P[tid];
}

// ============================ G = A^T @ inv(Phat_clamped) ============================
__global__ __launch_bounds__(256) void ginv_r14()
{
    const int idx = blockIdx.x;
    const int tt = idx/3 + 1, b = idx%3;
    const int tid = threadIdx.x;
    __shared__ float M[10][21];
    __shared__ float A[100];
    __shared__ int piv;
    if (tid < 100) {
        int i = tid/10, j = tid%10;
        M[i][j] = r14_phat[(tt*3+b)*100 + tid];
        M[i][10+j] = (i==j) ? 1.f : 0.f;
        A[tid] = r14_A[(tt*3+b)*100 + tid];
    }
    __syncthreads();
    const int r = tid/20, cc = tid%20;
    for (int k = 0; k < 10; k++) {
        if (tid == 0) {
            int p = k; float best = fabsf(M[k][k]);
            for (int rr = k+1; rr < 10; rr++) {
                float v = fabsf(M[rr][k]);
                if (v > best) { best = v; p = rr; }
            }
            piv = p;
        }
        __syncthreads();
        if (piv != k && tid < 20) {
            float a = M[k][tid], bb = M[piv][tid];
            M[k][tid] = bb; M[piv][tid] = a;
        }
        __syncthreads();
        float pinv = 1.f/safed(M[k][k]);
        float myf = 0.f, rowv = 0.f;
        if (tid < 200) { myf = M[r][k]; rowv = M[k][cc]; }
        __syncthreads();
        if (tid < 200) {
            if (r == k) M[k][cc] = rowv*pinv;
            else        M[r][cc] -= myf*pinv*rowv;
        }
        __syncthreads();
    }
    if (tid < 100) {
        int i = tid/10, j = tid%10;
        float s = 0.f;
        #pragma unroll
        for (int k = 0; k < 10; k++) s += A[k*10+i]*M[k][10+j];
        r14_G[(tt*3+b)*100 + tid] = s;
    }
}

// ============================ RTS smoother ============================
__global__ __launch_bounds__(128) void rts_r14(float* __restrict__ dout)
{
    const int b = blockIdx.x, tid = threadIdx.x;
    const int i10 = tid/10, j10 = tid%10;
    __shared__ float zc[10], Pc[100], D[100], Gt[100], pPm[100], ph[100],
                     zh[10], pzv[10], dz[10], T1[100], zn[10], Pnn[100];
    if (tid < 10)  zc[tid] = r14_pz[(127*3+b)*10 + tid];
    if (tid < 100) Pc[tid] = r14_pp[(127*3+b)*100 + tid];
    for (int t = 126; t >= 0; t--) {
        __syncthreads();
        if (tid < 100) {
            Gt[tid]  = r14_G[((t+1)*3+b)*100 + tid];
            pPm[tid] = r14_pp[(t*3+b)*100 + tid];
            ph[tid]  = r14_phat[((t+1)*3+b)*100 + tid];
        }
        if (tid < 10) {
            zh[tid]  = r14_zhat[((t+1)*3+b)*10 + tid];
            pzv[tid] = r14_pz[(t*3+b)*10 + tid];
        }
        __syncthreads();
        if (tid < 100){ float s=0.f; for (int k=0;k<10;k++) s += pPm[i10*10+k]*Gt[k*10+j10]; D[tid]=s; }
        if (tid < 10) dz[tid] = zc[tid] - zh[tid];
        __syncthreads();
        if (tid < 10) { float s=pzv[tid]; for (int k=0;k<10;k++) s += D[tid*10+k]*dz[k]; zn[tid]=s; }
        if (tid < 100){ float s=0.f; for (int k=0;k<10;k++) s += D[i10*10+k]*(Pc[k*10+j10]-ph[k*10+j10]); T1[tid]=s; }
        __syncthreads();
        if (tid < 100){ float s=pPm[tid]; for (int k=0;k<10;k++) s += T1[i10*10+k]*D[j10*10+k]; Pnn[tid]=s; }
        __syncthreads();
        if (tid < 10) { dout[OUT_ZS + (b*127+t)*10 + tid] = zn[tid]; zc[tid]=zn[tid]; }
        if (tid < 100){ dout[OUT_PS + (b*127+t)*100 + tid] = Pnn[tid]; Pc[tid]=Pnn[tid]; }
    }
}

// ============================ launch ============================
extern "C" void kernel_launch(void* const* d_in, const int* in_sizes, int n_in,
                              void* d_out, int out_size, void* d_ws, size_t ws_size,
                              hipStream_t stream)
{
    (void)in_sizes; (void)n_in; (void)out_size; (void)d_ws; (void)ws_size;
    const float* images = (const float*)d_in[0];
    const float* w1   = (const float*)d_in[1];
    const float* b1   = (const float*)d_in[2];
    const float* w2   = (const float*)d_in[3];
    const float* b2   = (const float*)d_in[4];
    const float* w3   = (const float*)d_in[5];
    const float* b3   = (const float*)d_in[6];
    const float* wd   = (const float*)d_in[7];
    const float* bd   = (const float*)d_in[8];
    const float* lk   = (const float*)d_in[9];
    const float* lrk  = (const float*)d_in[10];
    const float* lb   = (const float*)d_in[11];
    const float* wabc = (const float*)d_in[12];
    const float* babc = (const float*)d_in[13];
    float* dout = (float*)d_out;   // d_out is FLOAT32 (verified R10)

    u16 *c1p, *c2p, *w2hp, *w2lp, *w3hp, *w3lp;
    float *wdTp;
    hipGetSymbolAddress((void**)&c1p,  HIP_SYMBOL(r14_c1));
    hipGetSymbolAddress((void**)&c2p,  HIP_SYMBOL(r14_c2));
    hipGetSymbolAddress((void**)&w2hp, HIP_SYMBOL(r14_w2h));
    hipGetSymbolAddress((void**)&w2lp, HIP_SYMBOL(r14_w2l));
    hipGetSymbolAddress((void**)&w3hp, HIP_SYMBOL(r14_w3h));
    hipGetSymbolAddress((void**)&w3lp, HIP_SYMBOL(r14_w3l));
    hipGetSymbolAddress((void**)&wdTp, HIP_SYMBOL(r14_wdT));

    conv1_r14<<<dim3(384), dim3(256), 0, stream>>>(images, w1, b1, c1p);
    w2t_r14<<<dim3(512), dim3(256), 0, stream>>>(w2, w2hp, w2lp);
    w3t_r14<<<dim3(4096), dim3(256), 0, stream>>>(w3, w3hp, w3lp);
    wdt_r14<<<dim3(640), dim3(256), 0, stream>>>(wd, wdTp);
    conv2_r14<<<dim3(384, 2), dim3(256), 0, stream>>>(c1p, w2hp, w2lp, b2, c2p);
    conv3_r21<<<dim3(192, 4), dim3(256), 0, stream>>>(c2p, w3hp, w3lp, b3);
    lstm_r21<<<dim3(3), dim3(512), 0, stream>>>(lk, lrk, lb, bd, dout);
    abc_r14<<<dim3(384), dim3(192), 0, stream>>>(wabc, babc, dout);
    kf_r15<<<dim3(3), dim3(128), 0, stream>>>(dout);
    ginv_r14<<<dim3(381), dim3(256), 0, stream>>>();
    rts_r14<<<dim3(3), dim3(128), 0, stream>>>(dout);
}

// Round 10
// 822.539 us; speedup vs baseline: 1.3470x; 1.1091x over previous
//
#include <hip/hip_runtime.h>
#include <math.h>

typedef unsigned int   u32;
typedef unsigned short u16;
typedef short bf16x8 __attribute__((ext_vector_type(8)));
typedef float f32x4  __attribute__((ext_vector_type(4)));

// ---- output element offsets (d_out is FLOAT32, 101760 elements) ----
#define OUT_ZS    0
#define OUT_PS    3810
#define OUT_AALL  41910
#define OUT_A     43830
#define OUT_C     82230
#define OUT_LASTZ 101430
#define OUT_LASTP 101460

__device__ __forceinline__ float sigm(float x){ return 1.f/(1.f+expf(-x)); }
__device__ __forceinline__ float safed(float d){
    return (fabsf(d) < 1e-30f) ? ((d < 0.f) ? -1e-30f : 1e-30f) : d;
}
__device__ __forceinline__ u16 f2b(float f) {
    union { float f; u32 u; } v; v.f = f;
    u32 r = v.u + 0x7fffu + ((v.u >> 16) & 1u);   // RNE
    return (u16)(r >> 16);
}
__device__ __forceinline__ float b2f(u16 u) {
    union { u32 x; float f; } v; v.x = ((u32)u) << 16; return v.f;
}
__device__ __forceinline__ u32 packb(float a, float b){ return (u32)f2b(a) | ((u32)f2b(b) << 16); }

// ---- static device workspace ----
__device__ u16   r14_c1[25165824];   // conv1 out bf16 NHWC [384][32][32][64]
__device__ u16   r14_c2[12582912];   // conv2 out bf16 NHWC [384][16][16][128]
__device__ u16   r14_w2h[131072];    // w2T hi bf16 [128 oc][1024 k]
__device__ u16   r14_w2l[131072];    // w2T lo bf16
__device__ u16   r14_w3h[1048576];   // w3T hi bf16 [512 oc][2048 k]
__device__ u16   r14_w3l[1048576];   // w3T lo bf16
__device__ float r14_wdT[163840];    // [5][32768] compacted dense weights (5 used cols of 20)
__device__ float r20_dpart[7680];    // dense partials [384 f][4 ocg][5 d]
__device__ float r14_hs[49152];
__device__ float r14_zhat[3840];
__device__ float r14_phat[38400];
__device__ float r14_pz[3840];
__device__ float r14_pp[38400];
__device__ float r14_aall[1920];
__device__ float r14_A[38400];
__device__ float r14_C[19200];
__device__ float r14_G[38400];

// ============================ conv1 (fp32 VALU, bf16 NHWC out) ============================
__global__ __launch_bounds__(256) void conv1_r14(const float* __restrict__ img,
        const float* __restrict__ w1, const float* __restrict__ b1, u16* __restrict__ out)
{
    __shared__ float in_lds[66*66];
    const int f = blockIdx.x, tid = threadIdx.x;
    const int og = tid >> 5, sg = tid & 31;

    for (int i = tid; i < 66*66; i += 256) in_lds[i] = 0.f;
    __syncthreads();
    const float4* src = (const float4*)(img + f*4096);
    for (int i = tid; i < 1024; i += 256) {
        int r = i >> 4, c0 = (i & 15) * 4;
        float4 v = src[i];
        float* dst = &in_lds[(r+1)*66 + c0 + 1];
        dst[0]=v.x; dst[1]=v.y; dst[2]=v.z; dst[3]=v.w;
    }
    float wr[16][8];
    #pragma unroll
    for (int k = 0; k < 16; k++) {
        float4 a = *(const float4*)&w1[k*64 + og*8];
        float4 b = *(const float4*)&w1[k*64 + og*8 + 4];
        wr[k][0]=a.x; wr[k][1]=a.y; wr[k][2]=a.z; wr[k][3]=a.w;
        wr[k][4]=b.x; wr[k][5]=b.y; wr[k][6]=b.z; wr[k][7]=b.w;
    }
    float bias[8];
    #pragma unroll
    for (int j = 0; j < 8; j++) bias[j] = b1[og*8+j];
    __syncthreads();

    for (int yy = 0; yy < 32; yy++) {
        float inv[16];
        #pragma unroll
        for (int ky = 0; ky < 4; ky++)
            #pragma unroll
            for (int kx = 0; kx < 4; kx++)
                inv[ky*4+kx] = in_lds[(2*yy+ky)*66 + 2*sg+kx];
        float acc[8];
        #pragma unroll
        for (int j = 0; j < 8; j++) acc[j] = bias[j];
        #pragma unroll
        for (int k = 0; k < 16; k++)
            #pragma unroll
            for (int j = 0; j < 8; j++) acc[j] += inv[k]*wr[k][j];
        #pragma unroll
        for (int j = 0; j < 8; j++) acc[j] = fmaxf(acc[j], 0.f);
        uint4 pk = make_uint4(packb(acc[0],acc[1]), packb(acc[2],acc[3]),
                              packb(acc[4],acc[5]), packb(acc[6],acc[7]));
        *(uint4*)(out + (f*1024 + yy*32 + sg)*64 + og*8) = pk;
    }
}

// ============================ weight transpose + bf16 split ============================
__global__ __launch_bounds__(256) void w2t_r14(const float* __restrict__ w2,
        u16* __restrict__ hi, u16* __restrict__ lo)
{
    int idx = blockIdx.x*256 + threadIdx.x;
    if (idx < 131072) {
        int k = idx >> 7, oc = idx & 127;
        float v = w2[idx];
        u16 h = f2b(v);
        hi[oc*1024 + k] = h;
        lo[oc*1024 + k] = f2b(v - b2f(h));
    }
}
__global__ __launch_bounds__(256) void w3t_r14(const float* __restrict__ w3,
        u16* __restrict__ hi, u16* __restrict__ lo)
{
    int idx = blockIdx.x*256 + threadIdx.x;
    if (idx < 1048576) {
        int k = idx >> 9, oc = idx & 511;
        float v = w3[idx];
        u16 h = f2b(v);
        hi[oc*2048 + k] = h;
        lo[oc*2048 + k] = f2b(v - b2f(h));
    }
}
__global__ __launch_bounds__(256) void wdt_r14(const float* __restrict__ wd, float* __restrict__ wdT)
{
    int idx = blockIdx.x*256 + threadIdx.x;
    if (idx < 163840) {
        int j = idx & 32767, d = idx >> 15;
        wdT[d*32768 + j] = wd[j*20 + d];
    }
}

// ============================ conv2 MFMA (r14: per-tap staging) ============================
__global__ __launch_bounds__(256) void conv2_r14(const u16* __restrict__ c1b,
        const u16* __restrict__ w2h, const u16* __restrict__ w2l,
        const float* __restrict__ b2, u16* __restrict__ c2b)
{
    __shared__ __align__(16) u16 slab[128*72];
    const int f = blockIdx.x, mc = blockIdx.y, tid = threadIdx.x;
    const int wave = tid >> 6, lane = tid & 63, quad = lane >> 4, ln = lane & 15;

    f32x4 acc[8][2];
    const f32x4 zz = {0.f, 0.f, 0.f, 0.f};
    #pragma unroll
    for (int mt = 0; mt < 8; mt++) { acc[mt][0] = zz; acc[mt][1] = zz; }

    const int sp = tid >> 1;
    const int sy = mc*8 + (sp >> 4), sx = sp & 15;
    const int sic = (tid & 1) * 32;

    for (int kk = 0; kk < 16; kk++) {
        const int ky = kk >> 2, kx = kk & 3;
        __syncthreads();
        {
            int iy = 2*sy - 1 + ky, ix = 2*sx - 1 + kx;
            uint4* d4 = (uint4*)&slab[sp*72 + sic];
            if (iy >= 0 && iy < 32 && ix >= 0 && ix < 32) {
                const uint4* s4 = (const uint4*)&c1b[((f*32 + iy)*32 + ix)*64 + sic];
                d4[0]=s4[0]; d4[1]=s4[1]; d4[2]=s4[2]; d4[3]=s4[3];
            } else {
                uint4 z = make_uint4(0,0,0,0);
                d4[0]=z; d4[1]=z; d4[2]=z; d4[3]=z;
            }
        }
        __syncthreads();
        #pragma unroll
        for (int ks = 0; ks < 2; ks++) {
            bf16x8 af[8];
            #pragma unroll
            for (int mt = 0; mt < 8; mt++)
                af[mt] = *(const bf16x8*)&slab[(mt*16 + ln)*72 + ks*32 + quad*8];
            #pragma unroll
            for (int nt = 0; nt < 2; nt++) {
                const int oc = wave*32 + nt*16 + ln;
                const int kb = kk*64 + ks*32 + quad*8;
                bf16x8 bh = *(const bf16x8*)&w2h[oc*1024 + kb];
                bf16x8 bl = *(const bf16x8*)&w2l[oc*1024 + kb];
                #pragma unroll
                for (int mt = 0; mt < 8; mt++) {
                    acc[mt][nt] = __builtin_amdgcn_mfma_f32_16x16x32_bf16(af[mt], bh, acc[mt][nt], 0,0,0);
                    acc[mt][nt] = __builtin_amdgcn_mfma_f32_16x16x32_bf16(af[mt], bl, acc[mt][nt], 0,0,0);
                }
            }
        }
    }
    #pragma unroll
    for (int nt = 0; nt < 2; nt++) {
        const int oc = wave*32 + nt*16 + ln;
        const float bias = b2[oc];
        #pragma unroll
        for (int mt = 0; mt < 8; mt++)
            #pragma unroll
            for (int r = 0; r < 4; r++) {
                int pix = mc*128 + mt*16 + quad*4 + r;
                c2b[(f*256 + pix)*128 + oc] = f2b(fmaxf(acc[mt][nt][r] + bias, 0.f));
            }
    }
}

// ============================ conv3 MFMA (r21: 2-frame weight reuse + fused dense) ============================
// grid (192, 4): blockIdx.x = frame-pair fp, blockIdx.y = ocg (128 oc).
// Each weight fetch (bh/bl) feeds MFMAs for BOTH frames -> weight traffic per frame halved.
__global__ __launch_bounds__(256, 3) void conv3_r21(const u16* __restrict__ c2b,
        const u16* __restrict__ w3h, const u16* __restrict__ w3l,
        const float* __restrict__ b3)
{
    __shared__ __align__(16) u16 slab[2][64*136];
    const int fp = blockIdx.x, ocg = blockIdx.y, tid = threadIdx.x;
    const int wave = tid >> 6, lane = tid & 63, quad = lane >> 4, ln = lane & 15;
    const int wn = ocg*128 + wave*32;

    f32x4 acc[2][4][2];
    const f32x4 zz = {0.f, 0.f, 0.f, 0.f};
    #pragma unroll
    for (int f2 = 0; f2 < 2; f2++)
        #pragma unroll
        for (int mt = 0; mt < 4; mt++) { acc[f2][mt][0] = zz; acc[f2][mt][1] = zz; }

    const int sp = tid >> 2;
    const int sy = sp >> 3, sx = sp & 7;
    const int sic = (tid & 3) * 32;

    for (int kk = 0; kk < 16; kk++) {
        const int ky = kk >> 2, kx = kk & 3;
        const int iy = 2*sy - 1 + ky, ix = 2*sx - 1 + kx;
        const bool vin = (iy >= 0 && iy < 16 && ix >= 0 && ix < 16);
        __syncthreads();
        #pragma unroll
        for (int f2 = 0; f2 < 2; f2++) {
            const int f = fp*2 + f2;
            uint4* d4 = (uint4*)&slab[f2][sp*136 + sic];
            if (vin) {
                const uint4* s4 = (const uint4*)&c2b[((f*16 + iy)*16 + ix)*128 + sic];
                d4[0]=s4[0]; d4[1]=s4[1]; d4[2]=s4[2]; d4[3]=s4[3];
            } else {
                uint4 z = make_uint4(0,0,0,0);
                d4[0]=z; d4[1]=z; d4[2]=z; d4[3]=z;
            }
        }
        __syncthreads();
        #pragma unroll
        for (int ks = 0; ks < 4; ks++) {
            bf16x8 af[2][4];
            #pragma unroll
            for (int f2 = 0; f2 < 2; f2++)
                #pragma unroll
                for (int mt = 0; mt < 4; mt++)
                    af[f2][mt] = *(const bf16x8*)&slab[f2][(mt*16 + ln)*136 + ks*32 + quad*8];
            const int kb = kk*128 + ks*32 + quad*8;
            #pragma unroll
            for (int nt = 0; nt < 2; nt++) {
                const int oc = wn + nt*16 + ln;
                bf16x8 bh = *(const bf16x8*)&w3h[oc*2048 + kb];
                bf16x8 bl = *(const bf16x8*)&w3l[oc*2048 + kb];
                #pragma unroll
                for (int f2 = 0; f2 < 2; f2++)
                    #pragma unroll
                    for (int mt = 0; mt < 4; mt++) {
                        acc[f2][mt][nt] = __builtin_amdgcn_mfma_f32_16x16x32_bf16(af[f2][mt], bh, acc[f2][mt][nt], 0,0,0);
                        acc[f2][mt][nt] = __builtin_amdgcn_mfma_f32_16x16x32_bf16(af[f2][mt], bl, acc[f2][mt][nt], 0,0,0);
                    }
            }
        }
    }

    // fused dense partials (per frame) via compacted wdT
    float pd[2][5];
    #pragma unroll
    for (int f2 = 0; f2 < 2; f2++)
        #pragma unroll
        for (int d = 0; d < 5; d++) pd[f2][d] = 0.f;
    #pragma unroll
    for (int nt = 0; nt < 2; nt++) {
        const int oc = wn + nt*16 + ln;
        const float bias = b3[oc];
        #pragma unroll
        for (int mt = 0; mt < 4; mt++)
            #pragma unroll
            for (int r = 0; r < 4; r++) {
                const int pix = mt*16 + quad*4 + r;
                const float* wp = &r14_wdT[pix*512 + oc];
                const float w0 = wp[0], w1 = wp[32768], w2 = wp[65536],
                            w3v = wp[98304], w4 = wp[131072];
                #pragma unroll
                for (int f2 = 0; f2 < 2; f2++) {
                    const float v = fmaxf(acc[f2][mt][nt][r] + bias, 0.f);
                    pd[f2][0] += v*w0; pd[f2][1] += v*w1; pd[f2][2] += v*w2;
                    pd[f2][3] += v*w3v; pd[f2][4] += v*w4;
                }
            }
    }
    __syncthreads();                 // done reading slab as u16
    float* red = (float*)slab;       // [10][256] floats = 10 KB < 34 KB
    #pragma unroll
    for (int f2 = 0; f2 < 2; f2++)
        #pragma unroll
        for (int d = 0; d < 5; d++) red[(f2*5+d)*256 + tid] = pd[f2][d];
    __syncthreads();
    for (int st = 128; st > 0; st >>= 1) {
        if (tid < st) {
            #pragma unroll
            for (int q = 0; q < 10; q++) red[q*256+tid] += red[q*256+tid+st];
        }
        __syncthreads();
    }
    if (tid < 10) {
        const int f2 = tid/5, d = tid%5;
        r20_dpart[((fp*2+f2)*4 + ocg)*5 + d] = red[tid*256];
    }
}

// ============================ LSTM (r22: parallel gate activations) ============================
__global__ __launch_bounds__(512) void lstm_r22(const float* __restrict__ lk,
        const float* __restrict__ lrk, const float* __restrict__ lb,
        const float* __restrict__ bd, float* __restrict__ dout)
{
    const int b = blockIdx.x, c = threadIdx.x;   // c = gate column 0..511
    __shared__ float a_lds[640];
    __shared__ float h_lds[128];
    __shared__ float g_lds[512];                 // holds ACTIVATED gate values
    for (int i = c; i < 640; i += 512) {
        const int f = b*128 + i/5, d = i % 5;
        float v = bd[d];
        #pragma unroll
        for (int g = 0; g < 4; g++) v += r20_dpart[f*20 + g*5 + d];
        a_lds[i] = v;
        r14_aall[f*5 + d] = v;
        dout[OUT_AALL + f*5 + d] = v;
    }
    if (c < 128) h_lds[c] = 0.f;
    float wreg[128];                    // lrk column resident in VGPRs
    #pragma unroll
    for (int j = 0; j < 128; j++) wreg[j] = lrk[j*512 + c];
    float lkr[5];
    #pragma unroll
    for (int d = 0; d < 5; d++) lkr[d] = lk[d*512 + c];
    const float gb = lb[c];
    const bool is_gg = (c >= 256 && c < 384);   // wave-uniform (waves 4,5)
    float cs = 0.f;
    __syncthreads();
    for (int t = 0; t < 128; t++) {
        float g = gb;
        if (t > 0) {
            #pragma unroll
            for (int d = 0; d < 5; d++) g += a_lds[(t-1)*5 + d] * lkr[d];
        }
        float s0=0.f, s1=0.f, s2=0.f, s3=0.f;   // 4 chains to break fp-add dependence
        #pragma unroll
        for (int j = 0; j < 128; j += 4) {
            float4 h4 = *(const float4*)&h_lds[j];
            s0 += h4.x*wreg[j];   s1 += h4.y*wreg[j+1];
            s2 += h4.z*wreg[j+2]; s3 += h4.w*wreg[j+3];
        }
        g += (s0 + s1) + (s2 + s3);
        g_lds[c] = is_gg ? tanhf(g) : sigm(g);   // each lane applies its own gate's activation
        __syncthreads();
        if (c < 128) {
            float ai = g_lds[c], af_ = g_lds[c+128], ag = g_lds[c+256], ao = g_lds[c+384];
            cs = af_*cs + ai*ag;
            float hn = ao*tanhf(cs);
            h_lds[c] = hn;
            r14_hs[(t*3 + b)*128 + c] = hn;
        }
        __syncthreads();
    }
}

// ============================ abc -> A, C ============================
__global__ __launch_bounds__(192) void abc_r14(const float* __restrict__ wabc,
        const float* __restrict__ babc, float* __restrict__ dout)
{
    const int tb = blockIdx.x, c = threadIdx.x;
    __shared__ float h_lds[128];
    if (c < 128) h_lds[c] = r14_hs[tb*128 + c];
    __syncthreads();
    if (c < 150) {
        float s = babc[c];
        for (int j = 0; j < 128; j++) s += h_lds[j]*wabc[j*150 + c];
        if (c < 100) { r14_A[tb*100 + c] = s; dout[OUT_A + tb*100 + c] = s; }
        else         { r14_C[tb*50 + (c-100)] = s; dout[OUT_C + tb*50 + (c-100)] = s; }
    }
}

// ============================ Kalman filter (r22: prefetch+staging moved under solve cover) ============================
__global__ __launch_bounds__(128) void kf_r22(float* __restrict__ dout)
{
    const int b = blockIdx.x, tid = threadIdx.x;
    const int i10 = tid/10, j10 = tid%10;
    __shared__ float Ab[2][100], Cb[2][56], avb[2][8];
    __shared__ float z[12], P[100], zh[12], AP[100], Ph[100], resid[8],
                     CPm[52], PCt[52], Ssh[28], Kg[52];

    // prologue: init state, stage t=0, issue prefetch of t=1
    float rA = 0.f, rC = 0.f, rav = 0.f;
    if (tid < 100) rA  = r14_A[(0*3+b)*100 + tid];
    if (tid < 50)  rC  = r14_C[(0*3+b)*50 + tid];
    if (tid < 5)   rav = r14_aall[(b*128+0)*5 + tid];
    if (tid < 100) P[tid] = (i10==j10) ? 1.f : 0.f;
    if (tid < 10)  z[tid] = 0.f;
    if (tid < 100) Ab[0][tid] = rA;
    if (tid < 50)  Cb[0][tid] = rC;
    if (tid < 5)   avb[0][tid] = rav;
    if (tid < 100) rA  = r14_A[(1*3+b)*100 + tid];
    if (tid < 50)  rC  = r14_C[(1*3+b)*50 + tid];
    if (tid < 5)   rav = r14_aall[(b*128+1)*5 + tid];
    __syncthreads();

    for (int t = 0; t < 128; t++) {
        const int cb = t & 1, nb = cb ^ 1;
        const float* Ax = Ab[cb];
        const float* Cx = Cb[cb];

        // P1: AP = A@P (lanes 0-99) || zh = A@z (lanes 100-109)
        if (tid < 100) {
            float s = 0.f;
            #pragma unroll
            for (int k = 0; k < 10; k++) s += Ax[i10*10+k]*P[k*10+j10];
            AP[tid] = s;
        } else if (tid < 110) {
            const int i = tid - 100;
            float s = 0.f;
            #pragma unroll
            for (int k = 0; k < 10; k++) s += Ax[i*10+k]*z[k];
            zh[i] = s;
        }
        __syncthreads();

        // P2: Ph = AP@A^T + Q (lanes 0-99) || resid = a - C@zh (lanes 100-104)
        if (tid < 100) {
            float s = (i10==j10) ? 0.08f : 0.f;
            #pragma unroll
            for (int k = 0; k < 10; k++) s += AP[i10*10+k]*Ax[j10*10+k];
            Ph[tid] = s;
        } else if (tid < 105) {
            const int c = tid - 100;
            float s = avb[cb][c];
            #pragma unroll
            for (int k = 0; k < 10; k++) s -= Cx[c*10+k]*zh[k];
            resid[c] = s;
        }
        __syncthreads();

        // P3: CPm = C@Ph (lanes 0-49) || PCt = Ph@C^T (lanes 64-113)
        if (tid < 50) {
            const int i = tid/10, j = tid%10;
            float s = 0.f;
            #pragma unroll
            for (int k = 0; k < 10; k++) s += Cx[i*10+k]*Ph[k*10+j];
            CPm[tid] = s;
        } else if (tid >= 64 && tid < 114) {
            const int q = tid-64, i = q/5, j = q%5;
            float s = 0.f;
            #pragma unroll
            for (int k = 0; k < 10; k++) s += Ph[i*10+k]*Cx[j*10+k];
            PCt[q] = s;
        }
        __syncthreads();

        // P4: S = CPm@C^T + R (lanes 0-24)
        if (tid < 25) {
            const int i = tid/5, j = tid%5;
            float s = (i==j) ? 0.03f : 0.f;
            #pragma unroll
            for (int k = 0; k < 10; k++) s += CPm[i*10+k]*Cx[j*10+k];
            Ssh[tid] = s;
        }
        __syncthreads();

        // P5: stage next-step LDS bufs + issue t+2 prefetch (drain covered by solve),
        //     lanes 0-9 solve S^T y = PCt[i,:]^T in registers -> K row i.
        //     Safe: Ab/Cb/avb[cb] have no readers after P4; [nb] not read until t+1.
        if (t < 127) {
            if (tid < 100) Ab[nb][tid] = rA;
            if (tid < 50)  Cb[nb][tid] = rC;
            if (tid < 5)   avb[nb][tid] = rav;
            if (t < 126) {
                if (tid < 100) rA  = r14_A[((t+2)*3+b)*100 + tid];
                if (tid < 50)  rC  = r14_C[((t+2)*3+b)*50 + tid];
                if (tid < 5)   rav = r14_aall[(b*128+(t+2))*5 + tid];
            }
        }
        if (tid < 10) {
            float M[5][5], bb[5], pv[5], x[5];
            #pragma unroll
            for (int r = 0; r < 5; r++)
                #pragma unroll
                for (int c = 0; c < 5; c++) M[r][c] = Ssh[c*5+r];   // M = S^T
            #pragma unroll
            for (int k = 0; k < 5; k++) bb[k] = PCt[tid*5+k];
            #pragma unroll
            for (int k = 0; k < 5; k++) {
                const float p = 1.f/safed(M[k][k]);
                pv[k] = p;
                #pragma unroll
                for (int r = k+1; r < 5; r++) {
                    const float f = M[r][k]*p;
                    #pragma unroll
                    for (int c = k+1; c < 5; c++) M[r][c] -= f*M[k][c];
                    bb[r] -= f*bb[k];
                }
            }
            #pragma unroll
            for (int k = 4; k >= 0; k--) {
                float s = bb[k];
                #pragma unroll
                for (int c = k+1; c < 5; c++) s -= M[k][c]*x[c];
                x[k] = s*pv[k];
            }
            #pragma unroll
            for (int k = 0; k < 5; k++) Kg[tid*5+k] = x[k];
        }
        __syncthreads();

        // P6: Pn = Ph - K@CPm -> P, pz = zh + K@resid -> z, all stores
        if (tid < 100) {
            float s = Ph[tid];
            #pragma unroll
            for (int k = 0; k < 5; k++) s -= Kg[i10*5+k]*CPm[k*10+j10];
            r14_pp[(t*3+b)*100 + tid] = s;
            P[tid] = s;
            r14_phat[(t*3+b)*100 + tid] = fmaxf(Ph[tid], (i10==j10)?1e-4f:0.f);
            if (tid < 10) r14_zhat[(t*3+b)*10 + tid] = zh[tid];
        } else if (tid < 110) {
            const int i = tid - 100;
            float s = zh[i];
            #pragma unroll
            for (int k = 0; k < 5; k++) s += Kg[i*5+k]*resid[k];
            r14_pz[(t*3+b)*10 + i] = s;
            z[i] = s;
        }
        __syncthreads();
    }
    if (tid < 10)  dout[OUT_LASTZ + b*10 + tid]  = z[tid];
    if (tid < 100) dout[OUT_LASTP + b*100 + tid] = P[tid];
}

// ============================ G = A^T @ inv(Phat_clamped) ============================
__global__ __launch_bounds__(256) void ginv_r14()
{
    const int idx = blockIdx.x;
    const int tt = idx/3 + 1, b = idx%3;
    const int tid = threadIdx.x;
    __shared__ float M[10][21];
    __shared__ float A[100];
    __shared__ int piv;
    if (tid < 100) {
        int i = tid/10, j = tid%10;
        M[i][j] = r14_phat[(tt*3+b)*100 + tid];
        M[i][10+j] = (i==j) ? 1.f : 0.f;
        A[tid] = r14_A[(tt*3+b)*100 + tid];
    }
    __syncthreads();
    const int r = tid/20, cc = tid%20;
    for (int k = 0; k < 10; k++) {
        if (tid == 0) {
            int p = k; float best = fabsf(M[k][k]);
            for (int rr = k+1; rr < 10; rr++) {
                float v = fabsf(M[rr][k]);
                if (v > best) { best = v; p = rr; }
            }
            piv = p;
        }
        __syncthreads();
        if (piv != k && tid < 20) {
            float a = M[k][tid], bb = M[piv][tid];
            M[k][tid] = bb; M[piv][tid] = a;
        }
        __syncthreads();
        float pinv = 1.f/safed(M[k][k]);
        float myf = 0.f, rowv = 0.f;
        if (tid < 200) { myf = M[r][k]; rowv = M[k][cc]; }
        __syncthreads();
        if (tid < 200) {
            if (r == k) M[k][cc] = rowv*pinv;
            else        M[r][cc] -= myf*pinv*rowv;
        }
        __syncthreads();
    }
    if (tid < 100) {
        int i = tid/10, j = tid%10;
        float s = 0.f;
        #pragma unroll
        for (int k = 0; k < 10; k++) s += A[k*10+i]*M[k][10+j];
        r14_G[(tt*3+b)*100 + tid] = s;
    }
}

// ============================ RTS smoother (r22: 128 thr, 3 phases, register prefetch) ============================
// step t data: Gt=G[(t+1)], pPm=pp[t], ph=phat[(t+1)], zh=zhat[(t+1)], pzv=pz[t]
__global__ __launch_bounds__(128) void rts_r22(float* __restrict__ dout)
{
    const int b = blockIdx.x, tid = threadIdx.x;
    const int i10 = tid/10, j10 = tid%10;
    const bool hz = (tid >= 100 && tid < 110);
    const int zi = tid - 100;
    __shared__ float zc[12], Pc[100], D[100], dz[12], T1[100];
    __shared__ float Gtb[2][100], pPb[2][100], phb[2][100], zhb[2][12], pzb[2][12];

    // carry init
    if (tid < 10) zc[tid] = r14_pz[(127*3+b)*10 + tid];
    if (tid < 100) Pc[tid] = r14_pp[(127*3+b)*100 + tid];

    float g0=0.f, p0=0.f, f0=0.f, zr=0.f, pr=0.f;
    // stage t=126 into buf0
    if (tid < 100) {
        Gtb[0][tid] = r14_G[(127*3+b)*100 + tid];
        pPb[0][tid] = r14_pp[(126*3+b)*100 + tid];
        phb[0][tid] = r14_phat[(127*3+b)*100 + tid];
    }
    if (hz) {
        zhb[0][zi] = r14_zhat[(127*3+b)*10 + zi];
        pzb[0][zi] = r14_pz[(126*3+b)*10 + zi];
    }
    // prefetch t=125 into regs
    if (tid < 100) {
        g0 = r14_G[(126*3+b)*100 + tid];
        p0 = r14_pp[(125*3+b)*100 + tid];
        f0 = r14_phat[(126*3+b)*100 + tid];
    }
    if (hz) {
        zr = r14_zhat[(126*3+b)*10 + zi];
        pr = r14_pz[(125*3+b)*10 + zi];
    }
    __syncthreads();

    for (int t = 126; t >= 0; t--) {
        const int cb = (126 - t) & 1, nb = cb ^ 1;

        // P1: D = pPm @ Gt (lanes 0-99)  ||  dz = zc - zh (lanes 100-109)
        if (tid < 100) {
            float s = 0.f;
            #pragma unroll
            for (int k = 0; k < 10; k++) s += pPb[cb][i10*10+k]*Gtb[cb][k*10+j10];
            D[tid] = s;
        } else if (tid < 110) {
            dz[zi] = zc[zi] - zhb[cb][zi];
        }
        __syncthreads();

        // P2: T1 = D @ (Pc - ph) (lanes 0-99)  ||  zn (lanes 100-109)
        //     + stage bufs[nb] from regs + issue next loads (drain covered by T1)
        if (tid < 100) {
            float s = 0.f;
            #pragma unroll
            for (int k = 0; k < 10; k++) s += D[i10*10+k]*(Pc[k*10+j10] - phb[cb][k*10+j10]);
            T1[tid] = s;
        } else if (tid < 110) {
            float s2 = pzb[cb][zi];
            #pragma unroll
            for (int k = 0; k < 10; k++) s2 += D[zi*10+k]*dz[k];
            zc[zi] = s2;
            dout[OUT_ZS + (b*127+t)*10 + zi] = s2;
        }
        if (t > 0) {
            if (tid < 100) { Gtb[nb][tid] = g0; pPb[nb][tid] = p0; phb[nb][tid] = f0; }
            if (hz)        { zhb[nb][zi] = zr; pzb[nb][zi] = pr; }
            if (t > 1) {
                const int s2 = t - 2;
                if (tid < 100) {
                    g0 = r14_G[((s2+1)*3+b)*100 + tid];
                    p0 = r14_pp[(s2*3+b)*100 + tid];
                    f0 = r14_phat[((s2+1)*3+b)*100 + tid];
                }
                if (hz) {
                    zr = r14_zhat[((s2+1)*3+b)*10 + zi];
                    pr = r14_pz[(s2*3+b)*10 + zi];
                }
            }
        }
        __syncthreads();

        // P3: Pnn = pPm + T1@D^T (write Pc + dout)
        if (tid < 100) {
            float s = pPb[cb][tid];
            #pragma unroll
            for (int k = 0; k < 10; k++) s += T1[i10*10+k]*D[j10*10+k];
            dout[OUT_PS + (b*127+t)*100 + tid] = s;
            Pc[tid] = s;
        }
        __syncthreads();
    }
}

// ============================ launch ============================
extern "C" void kernel_launch(void* const* d_in, const int* in_sizes, int n_in,
                              void* d_out, int out_size, void* d_ws, size_t ws_size,
                              hipStream_t stream)
{
    (void)in_sizes; (void)n_in; (void)out_size; (void)d_ws; (void)ws_size;
    const float* images = (const float*)d_in[0];
    const float* w1   = (const float*)d_in[1];
    const float* b1   = (const float*)d_in[2];
    const float* w2   = (const float*)d_in[3];
    const float* b2   = (const float*)d_in[4];
    const float* w3   = (const float*)d_in[5];
    const float* b3   = (const float*)d_in[6];
    const float* wd   = (const float*)d_in[7];
    const float* bd   = (const float*)d_in[8];
    const float* lk   = (const float*)d_in[9];
    const float* lrk  = (const float*)d_in[10];
    const float* lb   = (const float*)d_in[11];
    const float* wabc = (const float*)d_in[12];
    const float* babc = (const float*)d_in[13];
    float* dout = (float*)d_out;   // d_out is FLOAT32 (verified R10)

    u16 *c1p, *c2p, *w2hp, *w2lp, *w3hp, *w3lp;
    float *wdTp;
    hipGetSymbolAddress((void**)&c1p,  HIP_SYMBOL(r14_c1));
    hipGetSymbolAddress((void**)&c2p,  HIP_SYMBOL(r14_c2));
    hipGetSymbolAddress((void**)&w2hp, HIP_SYMBOL(r14_w2h));
    hipGetSymbolAddress((void**)&w2lp, HIP_SYMBOL(r14_w2l));
    hipGetSymbolAddress((void**)&w3hp, HIP_SYMBOL(r14_w3h));
    hipGetSymbolAddress((void**)&w3lp, HIP_SYMBOL(r14_w3l));
    hipGetSymbolAddress((void**)&wdTp, HIP_SYMBOL(r14_wdT));

    conv1_r14<<<dim3(384), dim3(256), 0, stream>>>(images, w1, b1, c1p);
    w2t_r14<<<dim3(512), dim3(256), 0, stream>>>(w2, w2hp, w2lp);
    w3t_r14<<<dim3(4096), dim3(256), 0, stream>>>(w3, w3hp, w3lp);
    wdt_r14<<<dim3(640), dim3(256), 0, stream>>>(wd, wdTp);
    conv2_r14<<<dim3(384, 2), dim3(256), 0, stream>>>(c1p, w2hp, w2lp, b2, c2p);
    conv3_r21<<<dim3(192, 4), dim3(256), 0, stream>>>(c2p, w3hp, w3lp, b3);
    lstm_r22<<<dim3(3), dim3(512), 0, stream>>>(lk, lrk, lb, bd, dout);
    abc_r14<<<dim3(384), dim3(192), 0, stream>>>(wabc, babc, dout);
    kf_r22<<<dim3(3), dim3(128), 0, stream>>>(dout);
    ginv_r14<<<dim3(381), dim3(256), 0, stream>>>();
    rts_r22<<<dim3(3), dim3(128), 0, stream>>>(dout);
}